// Round 4
// baseline (2471.295 us; speedup 1.0000x reference)
//
#include <hip/hip_runtime.h>

typedef unsigned short u16;
typedef __attribute__((ext_vector_type(8))) short short8;
typedef __attribute__((ext_vector_type(4))) short short4v;
typedef __attribute__((ext_vector_type(4))) float f32x4;

#define DEV static __device__ __forceinline__

DEV float bf2f(u16 h) {
    union { unsigned int u; float f; } v; v.u = ((unsigned int)h) << 16; return v.f;
}
DEV u16 f2bf(float f) {
    union { float f; unsigned int u; } v; v.f = f;
    unsigned int r = (v.u + 0x7fff + ((v.u >> 16) & 1)) >> 16;
    return (u16)r;
}
// load element i of tensor p which is fp32 if f32 else bf16
DEV float ldx(const void* p, size_t i, int f32) {
    return f32 ? ((const float*)p)[i] : bf2f(((const u16*)p)[i]);
}

#define GLD16(g, l) __builtin_amdgcn_global_load_lds( \
    (const __attribute__((address_space(1))) void*)(g), \
    (__attribute__((address_space(3))) void*)(l), 16, 0, 0)

// Stage 8 bf16 elements (16B) for this thread at element offset eoff of P.
// bf16 source: async global->LDS.  fp32 source: load 8 floats, convert, write.
#define STAGE(P, pf32, eoff, dst8) do {                                        \
    if (!(pf32)) { GLD16(((const u16*)(P)) + (eoff), (dst8)); }                \
    else {                                                                     \
        const float* _p = ((const float*)(P)) + (eoff);                        \
        f32x4 _a = *(const f32x4*)_p, _b = *(const f32x4*)(_p + 4);            \
        short8 _s;                                                             \
        _s[0]=(short)f2bf(_a[0]); _s[1]=(short)f2bf(_a[1]);                    \
        _s[2]=(short)f2bf(_a[2]); _s[3]=(short)f2bf(_a[3]);                    \
        _s[4]=(short)f2bf(_b[0]); _s[5]=(short)f2bf(_b[1]);                    \
        _s[6]=(short)f2bf(_b[2]); _s[7]=(short)f2bf(_b[3]);                    \
        *(short8*)(dst8) = _s;                                                 \
    } } while (0)

// ---------------------------------------------------------------------------
// Probe: classify input dtype (flags[0]=1 -> fp32) and mask encoding
// (flags[1]=1 -> bool bytes).  x ~ N(0,1): if bf16, even u16s have sane
// exponents; if fp32, even u16s are mantissa bits (random exponent field).
// Padding mask tail (positions 512..2047 cover rows 0-1 tails): bool bytes
// read as int give values like 0x01010101 > 1; int32 gives only 0/1.
// ---------------------------------------------------------------------------
__global__ __launch_bounds__(64) void probe_kernel(
    const void* __restrict__ x, const void* __restrict__ pad,
    int* __restrict__ flags)
{
    const int lane = threadIdx.x;
    const u16* xu = (const u16*)x;
    const unsigned int e = (xu[lane * 2] >> 7) & 0xFF;
    const int sane = (e >= 0x70 && e <= 0x8F) ? 1 : 0;
    unsigned long long m = __ballot(sane);
    const int f32 = (__popcll(m) < 32) ? 1 : 0;

    const unsigned int* pi = (const unsigned int*)pad;
    int bytes = 0;
#pragma unroll
    for (int j = 0; j < 6; j++) {
        unsigned int v = pi[128 + j * 64 + lane];
        if (v > 1u) bytes = 1;
    }
    m = __ballot(bytes);
    if (lane == 0) { flags[0] = f32; flags[1] = (m != 0ULL) ? 1 : 0; }
}

// ---------------------------------------------------------------------------
// Shared GEMM core: 128x128 tile, BK=32, 256 threads (4 waves, 4x4 mfma each).
// A rows offset by a_row0 (row stride = K); W rows offset w_off elements
// (row stride ldw). Dual dtype staging per flags.
// ---------------------------------------------------------------------------
#define GEMM_CORE(Av, ASEL, a_row0, Wv, w_off, ldw, K)                        \
    __shared__ __align__(16) u16 As[128 * 32];                                \
    __shared__ __align__(16) u16 Bs[128 * 32];                                \
    const int inf32 = flags[0];                                               \
    const int af32  = (ASEL) ? inf32 : 0;                                     \
    const int tid  = threadIdx.x;                                             \
    const int lane = tid & 63;                                                \
    const int wave = tid >> 6;                                                \
    const int lc   = lane & 15;                                               \
    const int quad = lane >> 4;                                               \
    const int m0 = blockIdx.x * 128;                                          \
    const int n0 = blockIdx.y * 128;                                          \
    const int wm = (wave >> 1) * 64;                                          \
    const int wn = (wave & 1) * 64;                                           \
    const int r0 = tid >> 2;                                                  \
    const int ko = (tid & 3) * 8;                                             \
    f32x4 acc[4][4] = {};                                                     \
    for (int k0 = 0; k0 < (K); k0 += 32) {                                    \
        STAGE(Av, af32, ((size_t)(a_row0) + m0 + r0) * (K) + k0 + ko,         \
              &As[tid * 8]);                                                  \
        STAGE(Av, af32, ((size_t)(a_row0) + m0 + r0 + 64) * (K) + k0 + ko,    \
              &As[2048 + tid * 8]);                                           \
        STAGE(Wv, inf32, (size_t)(w_off) + (size_t)(n0 + r0) * (ldw) + k0 + ko,\
              &Bs[tid * 8]);                                                  \
        STAGE(Wv, inf32, (size_t)(w_off) + (size_t)(n0 + r0 + 64) * (ldw) + k0 + ko,\
              &Bs[2048 + tid * 8]);                                           \
        __syncthreads();                                                      \
        short8 afr[4], bfr[4];                                                \
        const int qd = quad * 8;                                              \
        _Pragma("unroll")                                                     \
        for (int mt = 0; mt < 4; mt++)                                        \
            afr[mt] = *(const short8*)&As[(wm + mt * 16 + lc) * 32 + qd];     \
        _Pragma("unroll")                                                     \
        for (int nt = 0; nt < 4; nt++)                                        \
            bfr[nt] = *(const short8*)&Bs[(wn + nt * 16 + lc) * 32 + qd];     \
        _Pragma("unroll")                                                     \
        for (int mt = 0; mt < 4; mt++)                                        \
            _Pragma("unroll")                                                 \
            for (int nt = 0; nt < 4; nt++)                                    \
                acc[mt][nt] = __builtin_amdgcn_mfma_f32_16x16x32_bf16(        \
                    afr[mt], bfr[nt], acc[mt][nt], 0, 0, 0);                  \
        __syncthreads();                                                      \
    }                                                                         \
    const int ce0 = n0 + wn + lc;                                             \
    const int re0 = m0 + wm + quad * 4;

// ---------------------------------------------------------------------------
// Generic GEMM: C[*,N] = A @ W^T + bias.  EPI: 0 bias, 1 +resid, 2 +relu.
// C is always bf16 scratch.
// ---------------------------------------------------------------------------
template<int EPI>
__global__ __launch_bounds__(256, 2) void gemm_bt(
    const void* __restrict__ A, int a_sel, long a_row0,
    const void* __restrict__ W, long w_off,
    const void* __restrict__ bias, long b_off,
    const void* __restrict__ resid, int r_sel, long r_row0,
    u16* __restrict__ C, long c_row0,
    int N, int K, int ldw, const int* __restrict__ flags)
{
    GEMM_CORE(A, a_sel, a_row0, W, w_off, ldw, K)
    const int rf32 = r_sel ? inf32 : 0;
#pragma unroll
    for (int mt = 0; mt < 4; mt++) {
#pragma unroll
        for (int nt = 0; nt < 4; nt++) {
            const int c = ce0 + nt * 16;
            const float bv = ldx(bias, (size_t)b_off + c, inf32);
#pragma unroll
            for (int i = 0; i < 4; i++) {
                const int r = re0 + mt * 16 + i;
                float v = acc[mt][nt][i] + bv;
                if (EPI == 1)
                    v += ldx(resid, ((size_t)r_row0 + r) * N + c, rf32);
                if (EPI == 2) v = fmaxf(v, 0.0f);
                C[((size_t)c_row0 + r) * N + c] = f2bf(v);
            }
        }
    }
}

// QKV GEMM (N=3072, K=1024): Q (scaled 1/8) -> global rows of Qo; K,V -> local.
__global__ __launch_bounds__(256, 2) void gemm_qkv(
    const void* __restrict__ A, long a_row0,
    const void* __restrict__ W, const void* __restrict__ bias,
    u16* __restrict__ Qo, u16* __restrict__ Ko, u16* __restrict__ Vo,
    const int* __restrict__ flags)
{
    GEMM_CORE(A, 1, a_row0, W, 0, 1024, 1024)
#pragma unroll
    for (int mt = 0; mt < 4; mt++) {
#pragma unroll
        for (int nt = 0; nt < 4; nt++) {
            const int c = ce0 + nt * 16;
            const float bv = ldx(bias, c, inf32);
            u16* dst; size_t roff; int cc; float sc;
            if (c < 1024)      { dst = Qo; roff = (size_t)a_row0; cc = c;        sc = 0.125f; }
            else if (c < 2048) { dst = Ko; roff = 0;              cc = c - 1024; sc = 1.0f; }
            else               { dst = Vo; roff = 0;              cc = c - 2048; sc = 1.0f; }
#pragma unroll
            for (int i = 0; i < 4; i++) {
                const int r = re0 + mt * 16 + i;
                dst[(roff + r) * 1024 + cc] = f2bf((acc[mt][nt][i] + bv) * sc);
            }
        }
    }
}

// fc2 chunk: Cacc[2048,1024] (init? bias+resid+ : +=) hc @ fc2_w_chunk^T (fp32)
__global__ __launch_bounds__(256, 2) void gemm_accf32(
    const void* __restrict__ A, const void* __restrict__ W, long w_off,
    const void* __restrict__ bias, const u16* __restrict__ resid, long r_row0,
    float* __restrict__ C, int ldw, int init, const int* __restrict__ flags)
{
    GEMM_CORE(A, 0, 0, W, w_off, ldw, 1024)
#pragma unroll
    for (int mt = 0; mt < 4; mt++) {
#pragma unroll
        for (int nt = 0; nt < 4; nt++) {
            const int c = ce0 + nt * 16;
            const float bv = ldx(bias, c, inf32);
#pragma unroll
            for (int i = 0; i < 4; i++) {
                const int r = re0 + mt * 16 + i;
                float v = acc[mt][nt][i];
                if (init) v += bv + bf2f(resid[((size_t)r_row0 + r) * 1024 + c]);
                else      v += C[(size_t)r * 1024 + c];
                C[(size_t)r * 1024 + c] = v;
            }
        }
    }
}

// ---------------------------------------------------------------------------
// Flash attention, quarter-batch (2 sequences). Q/O in-place in QO (global
// bf16 rows); K/V quarter-local. One block per (q-tile 64, b_local*16+h).
// ---------------------------------------------------------------------------
__global__ __launch_bounds__(256, 2) void attn_kernel(
    u16* __restrict__ QO, const u16* __restrict__ Ko,
    const u16* __restrict__ Vo, const void* __restrict__ pad,
    int b0, const int* __restrict__ flags)
{
    __shared__ __align__(16) u16 Qs[64 * 64];
    __shared__ __align__(16) u16 Ks[64 * 64];
    __shared__ __align__(16) u16 Vs[64 * 64];   // [hd][key]
    __shared__ __align__(16) u16 Ps[4][16 * 64];
    __shared__ float kbias[64];

    const int tid  = threadIdx.x;
    const int lane = tid & 63;
    const int w    = tid >> 6;
    const int lc   = lane & 15;
    const int quad = lane >> 4;
    const int qt = blockIdx.x;
    const int bl = blockIdx.y >> 4;       // 0..1 within quarter
    const int h  = blockIdx.y & 15;
    const int b  = b0 + bl;
    const int maskBytes = flags[1];

    // load this block's Q tile (64 rows x 64 dims), already scaled
#pragma unroll
    for (int it = 0; it < 2; it++) {
        const int ch = it * 256 + tid;
        const int r = ch >> 3, c = (ch & 7) * 8;
        *(short8*)&Qs[ch * 8] =
            *(const short8*)&QO[((size_t)(b * 1024 + qt * 64 + r)) * 1024 + h * 64 + c];
    }

    f32x4 o[4] = {};
    float m_i[4], l_i[4];
#pragma unroll
    for (int i = 0; i < 4; i++) { m_i[i] = -1e30f; l_i[i] = 0.0f; }

    for (int kt = 0; kt <= qt; kt++) {
        __syncthreads();
#pragma unroll
        for (int it = 0; it < 2; it++) {
            const int ch = it * 256 + tid;
            const int r = ch >> 3, c = (ch & 7) * 8;
            const size_t row = (size_t)(bl * 1024 + kt * 64 + r) * 1024 + h * 64;
            *(short8*)&Ks[ch * 8] = *(const short8*)&Ko[row + c];
            short8 vv = *(const short8*)&Vo[row + c];
#pragma unroll
            for (int j = 0; j < 8; j++)
                Vs[(c + j) * 64 + r] = (u16)vv[j];
        }
        if (tid < 64) {
            const int idx = b * 1024 + kt * 64 + tid;
            const int mv = maskBytes ? (int)((const unsigned char*)pad)[idx]
                                     : ((const int*)pad)[idx];
            kbias[tid] = mv ? -1e30f : 0.0f;
        }
        __syncthreads();

        // S = Q K^T
        short8 aq[2];
#pragma unroll
        for (int kc = 0; kc < 2; kc++)
            aq[kc] = *(const short8*)&Qs[(w * 16 + lc) * 64 + kc * 32 + quad * 8];

        f32x4 s[4];
#pragma unroll
        for (int nt = 0; nt < 4; nt++) {
            f32x4 z = {};
#pragma unroll
            for (int kc = 0; kc < 2; kc++) {
                short8 bk = *(const short8*)&Ks[(nt * 16 + lc) * 64 + kc * 32 + quad * 8];
                z = __builtin_amdgcn_mfma_f32_16x16x32_bf16(aq[kc], bk, z, 0, 0, 0);
            }
            s[nt] = z;
        }

        const int qg0 = qt * 64 + w * 16 + quad * 4;
#pragma unroll
        for (int nt = 0; nt < 4; nt++) {
            const int kg = kt * 64 + nt * 16 + lc;
            const float kb = kbias[nt * 16 + lc];
#pragma unroll
            for (int i = 0; i < 4; i++) {
                float sv = s[nt][i] + kb;
                if (kg > qg0 + i) sv = -1e30f;
                s[nt][i] = sv;
            }
        }

        float mnew[4], al[4], rs[4];
#pragma unroll
        for (int i = 0; i < 4; i++) {
            float rm = fmaxf(fmaxf(s[0][i], s[1][i]), fmaxf(s[2][i], s[3][i]));
            rm = fmaxf(rm, __shfl_xor(rm, 1));
            rm = fmaxf(rm, __shfl_xor(rm, 2));
            rm = fmaxf(rm, __shfl_xor(rm, 4));
            rm = fmaxf(rm, __shfl_xor(rm, 8));
            mnew[i] = fmaxf(m_i[i], rm);
            al[i] = exp2f((m_i[i] - mnew[i]) * 1.442695041f);
            rs[i] = 0.0f;
        }
#pragma unroll
        for (int nt = 0; nt < 4; nt++)
#pragma unroll
            for (int i = 0; i < 4; i++) {
                float p = exp2f((s[nt][i] - mnew[i]) * 1.442695041f);
                s[nt][i] = p;
                rs[i] += p;
            }
#pragma unroll
        for (int i = 0; i < 4; i++) {
            float r = rs[i];
            r += __shfl_xor(r, 1);
            r += __shfl_xor(r, 2);
            r += __shfl_xor(r, 4);
            r += __shfl_xor(r, 8);
            l_i[i] = l_i[i] * al[i] + r;
            m_i[i] = mnew[i];
        }

        // P -> LDS (wave-private strip), C layout -> [query][key]
#pragma unroll
        for (int nt = 0; nt < 4; nt++)
#pragma unroll
            for (int i = 0; i < 4; i++)
                Ps[w][(quad * 4 + i) * 64 + nt * 16 + lc] = f2bf(s[nt][i]);

        // O = O*alpha + P @ V
        short8 ap[2];
#pragma unroll
        for (int kc = 0; kc < 2; kc++)
            ap[kc] = *(const short8*)&Ps[w][lc * 64 + kc * 32 + quad * 8];
#pragma unroll
        for (int nt2 = 0; nt2 < 4; nt2++) {
            f32x4 oo = o[nt2];
#pragma unroll
            for (int i = 0; i < 4; i++) oo[i] *= al[i];
#pragma unroll
            for (int kc = 0; kc < 2; kc++) {
                short8 bv = *(const short8*)&Vs[(nt2 * 16 + lc) * 64 + kc * 32 + quad * 8];
                oo = __builtin_amdgcn_mfma_f32_16x16x32_bf16(ap[kc], bv, oo, 0, 0, 0);
            }
            o[nt2] = oo;
        }
    }

#pragma unroll
    for (int i = 0; i < 4; i++) {
        const float inv = l_i[i] > 0.0f ? 1.0f / l_i[i] : 0.0f;
#pragma unroll
        for (int nt2 = 0; nt2 < 4; nt2++) {
            const int r = qt * 64 + w * 16 + quad * 4 + i;
            const int d = nt2 * 16 + lc;
            QO[((size_t)(b * 1024 + r)) * 1024 + h * 64 + d] = f2bf(o[nt2][i] * inv);
        }
    }
}

// ---------------------------------------------------------------------------
// LayerNorm over E=1024, one block/row, biased variance, eps=1e-12.
// IN16: input bf16 vs fp32 (compile-time: it's my own buffer).
// OUTSEL: 0 -> always bf16 scratch; 1 -> follow flags[0] (final output).
// ---------------------------------------------------------------------------
template<int IN16, int OUTSEL>
__global__ __launch_bounds__(256) void ln_kernel(
    const void* __restrict__ yv, const void* __restrict__ w,
    const void* __restrict__ bb, void* __restrict__ o, long o_row0,
    const int* __restrict__ flags)
{
    const int row = blockIdx.x;
    const int tid = threadIdx.x;
    const int inf32 = flags[0];
    float x0, x1, x2, x3;
    if (IN16) {
        const u16* p = (const u16*)yv + (size_t)row * 1024 + tid * 4;
        short4v v = *(const short4v*)p;
        x0 = bf2f((u16)v[0]); x1 = bf2f((u16)v[1]);
        x2 = bf2f((u16)v[2]); x3 = bf2f((u16)v[3]);
    } else {
        const float* p = (const float*)yv + (size_t)row * 1024 + tid * 4;
        f32x4 v = *(const f32x4*)p;
        x0 = v[0]; x1 = v[1]; x2 = v[2]; x3 = v[3];
    }
    float s = x0 + x1 + x2 + x3;
    float q = x0 * x0 + x1 * x1 + x2 * x2 + x3 * x3;
#pragma unroll
    for (int off = 32; off; off >>= 1) {
        s += __shfl_xor(s, off);
        q += __shfl_xor(q, off);
    }
    __shared__ float sm[8];
    const int lane = tid & 63, wv = tid >> 6;
    if (lane == 0) { sm[wv] = s; sm[4 + wv] = q; }
    __syncthreads();
    const float ts = sm[0] + sm[1] + sm[2] + sm[3];
    const float tq = sm[4] + sm[5] + sm[6] + sm[7];
    const float mean = ts * (1.0f / 1024.0f);
    float var = tq * (1.0f / 1024.0f) - mean * mean;
    if (var < 0.0f) var = 0.0f;
    const float rinv = rsqrtf(var + 1e-12f);

    const size_t obase = ((size_t)o_row0 + row) * 1024 + tid * 4;
#pragma unroll
    for (int j = 0; j < 4; j++) {
        const int c = tid * 4 + j;
        float xv = (j == 0) ? x0 : (j == 1) ? x1 : (j == 2) ? x2 : x3;
        float v = ldx(w, c, inf32) * ((xv - mean) * rinv) + ldx(bb, c, inf32);
        if (OUTSEL && inf32) ((float*)o)[obase + j] = v;
        else                 ((u16*)o)[obase + j] = f2bf(v);
    }
}

// ---------------------------------------------------------------------------
extern "C" void kernel_launch(void* const* d_in, const int* in_sizes, int n_in,
                              void* d_out, int out_size, void* d_ws, size_t ws_size,
                              hipStream_t stream)
{
    const void* x     = d_in[0];
    const void* in_w  = d_in[1];
    const void* in_b  = d_in[2];
    const void* out_w = d_in[3];
    const void* out_b = d_in[4];
    const void* fc1_w = d_in[5];
    const void* fc1_b = d_in[6];
    const void* fc2_w = d_in[7];
    const void* fc2_b = d_in[8];
    const void* ln1w  = d_in[9];
    const void* ln1b  = d_in[10];
    const void* ln2w  = d_in[11];
    const void* ln2b  = d_in[12];
    const void* pad   = d_in[13];
    u16* outp = (u16*)d_out;   // used as bf16 scratch regardless of out dtype

    // Workspace budget: 12 MB + 8 B.
    //   attn phase (per quarter): Ko ws[0,4M), Vo ws[4M,8M)
    //   proj phase (per half):    y1h ws[0,8M)
    //   FF phase (per quarter):   acc fp32 ws[0,8M), hc ws[8M,12M)
    //   flags at ws+12M (never overlapped)
    char* ws = (char*)d_ws;
    u16*   Ko    = (u16*)(ws + 0);
    u16*   Vo    = (u16*)(ws + 4194304);
    u16*   y1h   = (u16*)(ws + 0);
    float* acc   = (float*)(ws + 0);
    u16*   hc    = (u16*)(ws + 8388608);
    int*   flags = (int*)(ws + 12582912);

    dim3 blk(256);

    probe_kernel<<<dim3(1), dim3(64), 0, stream>>>(x, pad, flags);

    // attention phase: quarter-batch (2 sequences = 2048 rows) at a time
    for (int q = 0; q < 4; q++) {
        const long r0 = (long)q * 2048;
        gemm_qkv<<<dim3(16, 24), blk, 0, stream>>>(
            x, r0, in_w, in_b, outp, Ko, Vo, flags);
        attn_kernel<<<dim3(16, 32), blk, 0, stream>>>(
            outp, Ko, Vo, pad, q * 2, flags);
    }

    // out-proj + LN1, per half (4096 rows): y1h = O @ out_w^T + out_b + x;
    // x1 = LN1(y1h) written over O rows in d_out (bf16 scratch).
    for (int hf = 0; hf < 2; hf++) {
        const long r0 = (long)hf * 4096;
        gemm_bt<1><<<dim3(32, 8), blk, 0, stream>>>(
            outp, 0, r0, out_w, 0, out_b, 0, x, 1, r0,
            y1h, 0, 1024, 1024, 1024, flags);
        ln_kernel<1, 0><<<dim3(4096), blk, 0, stream>>>(
            y1h, ln1w, ln1b, outp, r0, flags);
    }

    // FF per quarter (2048 rows), REVERSE order so a possible fp32 final
    // output write (4 B/elem) never clobbers still-live bf16 x1 scratch.
    for (int q = 3; q >= 0; q--) {
        const long r0 = (long)q * 2048;
        for (int c = 0; c < 4; c++) {
            // hc = relu(x1_q @ fc1_w[c]^T + fc1_b[c])
            gemm_bt<2><<<dim3(16, 8), blk, 0, stream>>>(
                outp, 0, r0, fc1_w, (long)c * 1024 * 1024, fc1_b, (long)c * 1024,
                nullptr, 0, 0, hc, 0, 1024, 1024, 1024, flags);
            // acc (+)= hc @ fc2_w[:,c]^T (+bias+resid on first chunk)
            gemm_accf32<<<dim3(16, 8), blk, 0, stream>>>(
                hc, fc2_w, (long)c * 1024, fc2_b, outp, r0,
                acc, 4096, c == 0, flags);
        }
        ln_kernel<0, 1><<<dim3(2048), blk, 0, stream>>>(
            acc, ln2w, ln2b, d_out, r0, flags);
    }
}

// Round 5
// 821.547 us; speedup vs baseline: 3.0081x; 3.0081x over previous
//
#include <hip/hip_runtime.h>

typedef unsigned short u16;
typedef __attribute__((ext_vector_type(8))) short short8;
typedef __attribute__((ext_vector_type(4))) short short4v;
typedef __attribute__((ext_vector_type(4))) float f32x4;

#define DEV static __device__ __forceinline__

DEV float bf2f(u16 h) {
    union { unsigned int u; float f; } v; v.u = ((unsigned int)h) << 16; return v.f;
}
DEV u16 f2bf(float f) {
    union { float f; unsigned int u; } v; v.f = f;
    unsigned int r = (v.u + 0x7fff + ((v.u >> 16) & 1)) >> 16;
    return (u16)r;
}
// load element i of tensor p which is fp32 if f32 else bf16
DEV float ldx(const void* p, size_t i, int f32) {
    return f32 ? ((const float*)p)[i] : bf2f(((const u16*)p)[i]);
}

#define GLD16(g, l) __builtin_amdgcn_global_load_lds( \
    (const __attribute__((address_space(1))) void*)(g), \
    (__attribute__((address_space(3))) void*)(l), 16, 0, 0)

// Stage 8 bf16 elements (16B) at element offset eoff of P (bf16 or fp32).
#define STAGE(P, pf32, eoff, dst8) do {                                        \
    if (!(pf32)) { GLD16(((const u16*)(P)) + (eoff), (dst8)); }                \
    else {                                                                     \
        const float* _p = ((const float*)(P)) + (eoff);                        \
        f32x4 _a = *(const f32x4*)_p, _b = *(const f32x4*)(_p + 4);            \
        short8 _s;                                                             \
        _s[0]=(short)f2bf(_a[0]); _s[1]=(short)f2bf(_a[1]);                    \
        _s[2]=(short)f2bf(_a[2]); _s[3]=(short)f2bf(_a[3]);                    \
        _s[4]=(short)f2bf(_b[0]); _s[5]=(short)f2bf(_b[1]);                    \
        _s[6]=(short)f2bf(_b[2]); _s[7]=(short)f2bf(_b[3]);                    \
        *(short8*)(dst8) = _s;                                                 \
    } } while (0)

// ---------------------------------------------------------------------------
// Probe: flags[0]=1 -> inputs fp32; flags[1]=1 -> mask is bool bytes.
// Also writes flagsA = {0,0} (the "already bf16" flag set for converted bufs).
// ---------------------------------------------------------------------------
__global__ __launch_bounds__(64) void probe_kernel(
    const void* __restrict__ x, const void* __restrict__ pad,
    int* __restrict__ flags, int* __restrict__ flagsA)
{
    const int lane = threadIdx.x;
    const u16* xu = (const u16*)x;
    const unsigned int e = (xu[lane * 2] >> 7) & 0xFF;
    const int sane = (e >= 0x70 && e <= 0x8F) ? 1 : 0;
    unsigned long long m = __ballot(sane);
    const int f32 = (__popcll(m) < 32) ? 1 : 0;

    const unsigned int* pi = (const unsigned int*)pad;
    int bytes = 0;
#pragma unroll
    for (int j = 0; j < 6; j++) {
        unsigned int v = pi[128 + j * 64 + lane];
        if (v > 1u) bytes = 1;
    }
    m = __ballot(bytes);
    if (lane == 0) {
        flags[0] = f32; flags[1] = (m != 0ULL) ? 1 : 0;
        flagsA[0] = 0;  flagsA[1] = 0;
    }
}

// Convert/copy n4*4 elements to bf16 (src fp32 or bf16 per flags[0]).
__global__ __launch_bounds__(256) void conv4(
    const void* __restrict__ src, u16* __restrict__ dst, int n4,
    const int* __restrict__ flags)
{
    const int i = blockIdx.x * 256 + threadIdx.x;
    if (i >= n4) return;
    if (flags[0]) {
        f32x4 v = ((const f32x4*)src)[i];
        short4v s;
        s[0] = (short)f2bf(v[0]); s[1] = (short)f2bf(v[1]);
        s[2] = (short)f2bf(v[2]); s[3] = (short)f2bf(v[3]);
        ((short4v*)dst)[i] = s;
    } else {
        ((short4v*)dst)[i] = ((const short4v*)src)[i];
    }
}

// Mask [8192] -> float bias (-1e30 padded / 0), handling byte vs int32.
__global__ __launch_bounds__(256) void mask_to_bias(
    const void* __restrict__ pad, float* __restrict__ out,
    const int* __restrict__ flags)
{
    const int i = blockIdx.x * 256 + threadIdx.x;
    const int mv = flags[1] ? (int)((const unsigned char*)pad)[i]
                            : ((const int*)pad)[i];
    out[i] = mv ? -1e30f : 0.0f;
}

// ---------------------------------------------------------------------------
// Shared GEMM core: 128x128 tile, BK=32, 256 threads (4 waves, 4x4 mfma each).
// ---------------------------------------------------------------------------
#define GEMM_CORE(Av, ASEL, a_row0, Wv, w_off, ldw, K)                        \
    __shared__ __align__(16) u16 As[128 * 32];                                \
    __shared__ __align__(16) u16 Bs[128 * 32];                                \
    const int inf32 = flags[0];                                               \
    const int af32  = (ASEL) ? inf32 : 0;                                     \
    const int tid  = threadIdx.x;                                             \
    const int lane = tid & 63;                                                \
    const int wave = tid >> 6;                                                \
    const int lc   = lane & 15;                                               \
    const int quad = lane >> 4;                                               \
    const int m0 = blockIdx.x * 128;                                          \
    const int n0 = blockIdx.y * 128;                                          \
    const int wm = (wave >> 1) * 64;                                          \
    const int wn = (wave & 1) * 64;                                           \
    const int r0 = tid >> 2;                                                  \
    const int ko = (tid & 3) * 8;                                             \
    f32x4 acc[4][4] = {};                                                     \
    for (int k0 = 0; k0 < (K); k0 += 32) {                                    \
        STAGE(Av, af32, ((size_t)(a_row0) + m0 + r0) * (K) + k0 + ko,         \
              &As[tid * 8]);                                                  \
        STAGE(Av, af32, ((size_t)(a_row0) + m0 + r0 + 64) * (K) + k0 + ko,    \
              &As[2048 + tid * 8]);                                           \
        STAGE(Wv, inf32, (size_t)(w_off) + (size_t)(n0 + r0) * (ldw) + k0 + ko,\
              &Bs[tid * 8]);                                                  \
        STAGE(Wv, inf32, (size_t)(w_off) + (size_t)(n0 + r0 + 64) * (ldw) + k0 + ko,\
              &Bs[2048 + tid * 8]);                                           \
        __syncthreads();                                                      \
        short8 afr[4], bfr[4];                                                \
        const int qd = quad * 8;                                              \
        _Pragma("unroll")                                                     \
        for (int mt = 0; mt < 4; mt++)                                        \
            afr[mt] = *(const short8*)&As[(wm + mt * 16 + lc) * 32 + qd];     \
        _Pragma("unroll")                                                     \
        for (int nt = 0; nt < 4; nt++)                                        \
            bfr[nt] = *(const short8*)&Bs[(wn + nt * 16 + lc) * 32 + qd];     \
        _Pragma("unroll")                                                     \
        for (int mt = 0; mt < 4; mt++)                                        \
            _Pragma("unroll")                                                 \
            for (int nt = 0; nt < 4; nt++)                                    \
                acc[mt][nt] = __builtin_amdgcn_mfma_f32_16x16x32_bf16(        \
                    afr[mt], bfr[nt], acc[mt][nt], 0, 0, 0);                  \
        __syncthreads();                                                      \
    }                                                                         \
    const int ce0 = n0 + wn + lc;                                             \
    const int re0 = m0 + wm + quad * 4;

// Generic GEMM: C = A @ W^T + bias.  EPI: 0 bias, 1 +resid, 2 +relu.
template<int EPI>
__global__ __launch_bounds__(256, 2) void gemm_bt(
    const void* __restrict__ A, int a_sel, long a_row0,
    const void* __restrict__ W, long w_off,
    const void* __restrict__ bias, long b_off,
    const void* __restrict__ resid, int r_sel, long r_row0,
    u16* __restrict__ C, long c_row0,
    int N, int K, int ldw, const int* __restrict__ flags)
{
    GEMM_CORE(A, a_sel, a_row0, W, w_off, ldw, K)
    const int rf32 = r_sel ? inf32 : 0;
#pragma unroll
    for (int mt = 0; mt < 4; mt++) {
#pragma unroll
        for (int nt = 0; nt < 4; nt++) {
            const int c = ce0 + nt * 16;
            const float bv = ldx(bias, (size_t)b_off + c, inf32);
#pragma unroll
            for (int i = 0; i < 4; i++) {
                const int r = re0 + mt * 16 + i;
                float v = acc[mt][nt][i] + bv;
                if (EPI == 1)
                    v += ldx(resid, ((size_t)r_row0 + r) * N + c, rf32);
                if (EPI == 2) v = fmaxf(v, 0.0f);
                C[((size_t)c_row0 + r) * N + c] = f2bf(v);
            }
        }
    }
}

// QKV GEMM (N=3072): Q (scaled 1/8) -> global rows of Qo; K,V -> local rows.
__global__ __launch_bounds__(256, 2) void gemm_qkv(
    const void* __restrict__ A, long a_row0,
    const void* __restrict__ W, const void* __restrict__ bias,
    u16* __restrict__ Qo, u16* __restrict__ Ko, u16* __restrict__ Vo,
    const int* __restrict__ flags)
{
    GEMM_CORE(A, 1, a_row0, W, 0, 1024, 1024)
#pragma unroll
    for (int mt = 0; mt < 4; mt++) {
#pragma unroll
        for (int nt = 0; nt < 4; nt++) {
            const int c = ce0 + nt * 16;
            const float bv = ldx(bias, c, inf32);
            u16* dst; size_t roff; int cc; float sc;
            if (c < 1024)      { dst = Qo; roff = (size_t)a_row0; cc = c;        sc = 0.125f; }
            else if (c < 2048) { dst = Ko; roff = 0;              cc = c - 1024; sc = 1.0f; }
            else               { dst = Vo; roff = 0;              cc = c - 2048; sc = 1.0f; }
#pragma unroll
            for (int i = 0; i < 4; i++) {
                const int r = re0 + mt * 16 + i;
                dst[(roff + r) * 1024 + cc] = f2bf((acc[mt][nt][i] + bv) * sc);
            }
        }
    }
}

// fc2 chunk: Cacc (init? bias+resid+ : +=) A @ W_chunk^T, fp32 accumulator
__global__ __launch_bounds__(256, 2) void gemm_accf32(
    const void* __restrict__ A, const void* __restrict__ W, long w_off,
    const void* __restrict__ bias, const u16* __restrict__ resid, long r_row0,
    float* __restrict__ C, int ldw, int init, const int* __restrict__ flags)
{
    GEMM_CORE(A, 0, 0, W, w_off, ldw, 1024)
#pragma unroll
    for (int mt = 0; mt < 4; mt++) {
#pragma unroll
        for (int nt = 0; nt < 4; nt++) {
            const int c = ce0 + nt * 16;
            const float bv = ldx(bias, c, inf32);
#pragma unroll
            for (int i = 0; i < 4; i++) {
                const int r = re0 + mt * 16 + i;
                float v = acc[mt][nt][i];
                if (init) v += bv + bf2f(resid[((size_t)r_row0 + r) * 1024 + c]);
                else      v += C[(size_t)r * 1024 + c];
                C[(size_t)r * 1024 + c] = v;
            }
        }
    }
}

// ---------------------------------------------------------------------------
// Flash attention, in-place Q->O in QO (global rows b*1024+..).  K/V buffers
// indexed by local rows bl*1024+..  (bl = blockIdx.y>>4, b = b0+bl).
// kb: precomputed float mask bias [8192].
// ---------------------------------------------------------------------------
__global__ __launch_bounds__(256, 2) void attn_kernel(
    u16* __restrict__ QO, const u16* __restrict__ Ko,
    const u16* __restrict__ Vo, const float* __restrict__ kb, int b0)
{
    __shared__ __align__(16) u16 Qs[64 * 64];
    __shared__ __align__(16) u16 Ks[64 * 64];
    __shared__ __align__(16) u16 Vs[64 * 64];   // [hd][key]
    __shared__ __align__(16) u16 Ps[4][16 * 64];
    __shared__ float kbias[64];

    const int tid  = threadIdx.x;
    const int lane = tid & 63;
    const int w    = tid >> 6;
    const int lc   = lane & 15;
    const int quad = lane >> 4;
    const int qt = blockIdx.x;
    const int bl = blockIdx.y >> 4;
    const int h  = blockIdx.y & 15;
    const int b  = b0 + bl;

#pragma unroll
    for (int it = 0; it < 2; it++) {
        const int ch = it * 256 + tid;
        const int r = ch >> 3, c = (ch & 7) * 8;
        *(short8*)&Qs[ch * 8] =
            *(const short8*)&QO[((size_t)(b * 1024 + qt * 64 + r)) * 1024 + h * 64 + c];
    }

    f32x4 o[4] = {};
    float m_i[4], l_i[4];
#pragma unroll
    for (int i = 0; i < 4; i++) { m_i[i] = -1e30f; l_i[i] = 0.0f; }

    for (int kt = 0; kt <= qt; kt++) {
        __syncthreads();
#pragma unroll
        for (int it = 0; it < 2; it++) {
            const int ch = it * 256 + tid;
            const int r = ch >> 3, c = (ch & 7) * 8;
            const size_t row = (size_t)(bl * 1024 + kt * 64 + r) * 1024 + h * 64;
            *(short8*)&Ks[ch * 8] = *(const short8*)&Ko[row + c];
            short8 vv = *(const short8*)&Vo[row + c];
#pragma unroll
            for (int j = 0; j < 8; j++)
                Vs[(c + j) * 64 + r] = (u16)vv[j];
        }
        if (tid < 64)
            kbias[tid] = kb[b * 1024 + kt * 64 + tid];
        __syncthreads();

        short8 aq[2];
#pragma unroll
        for (int kc = 0; kc < 2; kc++)
            aq[kc] = *(const short8*)&Qs[(w * 16 + lc) * 64 + kc * 32 + quad * 8];

        f32x4 s[4];
#pragma unroll
        for (int nt = 0; nt < 4; nt++) {
            f32x4 z = {};
#pragma unroll
            for (int kc = 0; kc < 2; kc++) {
                short8 bk = *(const short8*)&Ks[(nt * 16 + lc) * 64 + kc * 32 + quad * 8];
                z = __builtin_amdgcn_mfma_f32_16x16x32_bf16(aq[kc], bk, z, 0, 0, 0);
            }
            s[nt] = z;
        }

        const int qg0 = qt * 64 + w * 16 + quad * 4;
#pragma unroll
        for (int nt = 0; nt < 4; nt++) {
            const int kg = kt * 64 + nt * 16 + lc;
            const float kbv = kbias[nt * 16 + lc];
#pragma unroll
            for (int i = 0; i < 4; i++) {
                float sv = s[nt][i] + kbv;
                if (kg > qg0 + i) sv = -1e30f;
                s[nt][i] = sv;
            }
        }

        float mnew[4], al[4], rs[4];
#pragma unroll
        for (int i = 0; i < 4; i++) {
            float rm = fmaxf(fmaxf(s[0][i], s[1][i]), fmaxf(s[2][i], s[3][i]));
            rm = fmaxf(rm, __shfl_xor(rm, 1));
            rm = fmaxf(rm, __shfl_xor(rm, 2));
            rm = fmaxf(rm, __shfl_xor(rm, 4));
            rm = fmaxf(rm, __shfl_xor(rm, 8));
            mnew[i] = fmaxf(m_i[i], rm);
            al[i] = exp2f((m_i[i] - mnew[i]) * 1.442695041f);
            rs[i] = 0.0f;
        }
#pragma unroll
        for (int nt = 0; nt < 4; nt++)
#pragma unroll
            for (int i = 0; i < 4; i++) {
                float p = exp2f((s[nt][i] - mnew[i]) * 1.442695041f);
                s[nt][i] = p;
                rs[i] += p;
            }
#pragma unroll
        for (int i = 0; i < 4; i++) {
            float r = rs[i];
            r += __shfl_xor(r, 1);
            r += __shfl_xor(r, 2);
            r += __shfl_xor(r, 4);
            r += __shfl_xor(r, 8);
            l_i[i] = l_i[i] * al[i] + r;
            m_i[i] = mnew[i];
        }

#pragma unroll
        for (int nt = 0; nt < 4; nt++)
#pragma unroll
            for (int i = 0; i < 4; i++)
                Ps[w][(quad * 4 + i) * 64 + nt * 16 + lc] = f2bf(s[nt][i]);

        short8 ap[2];
#pragma unroll
        for (int kc = 0; kc < 2; kc++)
            ap[kc] = *(const short8*)&Ps[w][lc * 64 + kc * 32 + quad * 8];
#pragma unroll
        for (int nt2 = 0; nt2 < 4; nt2++) {
            f32x4 oo = o[nt2];
#pragma unroll
            for (int i = 0; i < 4; i++) oo[i] *= al[i];
#pragma unroll
            for (int kc = 0; kc < 2; kc++) {
                short8 bv = *(const short8*)&Vs[(nt2 * 16 + lc) * 64 + kc * 32 + quad * 8];
                oo = __builtin_amdgcn_mfma_f32_16x16x32_bf16(ap[kc], bv, oo, 0, 0, 0);
            }
            o[nt2] = oo;
        }
    }

#pragma unroll
    for (int i = 0; i < 4; i++) {
        const float inv = l_i[i] > 0.0f ? 1.0f / l_i[i] : 0.0f;
#pragma unroll
        for (int nt2 = 0; nt2 < 4; nt2++) {
            const int r = qt * 64 + w * 16 + quad * 4 + i;
            const int d = nt2 * 16 + lc;
            QO[((size_t)(b * 1024 + r)) * 1024 + h * 64 + d] = f2bf(o[nt2][i] * inv);
        }
    }
}

// ---------------------------------------------------------------------------
// LayerNorm, one block/row, biased variance, eps=1e-12.
// ---------------------------------------------------------------------------
template<int IN16, int OUTSEL>
__global__ __launch_bounds__(256) void ln_kernel(
    const void* __restrict__ yv, const void* __restrict__ w,
    const void* __restrict__ bb, void* __restrict__ o, long o_row0,
    const int* __restrict__ flags)
{
    const int row = blockIdx.x;
    const int tid = threadIdx.x;
    const int inf32 = flags[0];
    float x0, x1, x2, x3;
    if (IN16) {
        const u16* p = (const u16*)yv + (size_t)row * 1024 + tid * 4;
        short4v v = *(const short4v*)p;
        x0 = bf2f((u16)v[0]); x1 = bf2f((u16)v[1]);
        x2 = bf2f((u16)v[2]); x3 = bf2f((u16)v[3]);
    } else {
        const float* p = (const float*)yv + (size_t)row * 1024 + tid * 4;
        f32x4 v = *(const f32x4*)p;
        x0 = v[0]; x1 = v[1]; x2 = v[2]; x3 = v[3];
    }
    float s = x0 + x1 + x2 + x3;
    float q = x0 * x0 + x1 * x1 + x2 * x2 + x3 * x3;
#pragma unroll
    for (int off = 32; off; off >>= 1) {
        s += __shfl_xor(s, off);
        q += __shfl_xor(q, off);
    }
    __shared__ float sm[8];
    const int lane = tid & 63, wv = tid >> 6;
    if (lane == 0) { sm[wv] = s; sm[4 + wv] = q; }
    __syncthreads();
    const float ts = sm[0] + sm[1] + sm[2] + sm[3];
    const float tq = sm[4] + sm[5] + sm[6] + sm[7];
    const float mean = ts * (1.0f / 1024.0f);
    float var = tq * (1.0f / 1024.0f) - mean * mean;
    if (var < 0.0f) var = 0.0f;
    const float rinv = rsqrtf(var + 1e-12f);

    const size_t obase = ((size_t)o_row0 + row) * 1024 + tid * 4;
#pragma unroll
    for (int j = 0; j < 4; j++) {
        const int c = tid * 4 + j;
        float xv = (j == 0) ? x0 : (j == 1) ? x1 : (j == 2) ? x2 : x3;
        float v = ldx(w, c, inf32) * ((xv - mean) * rinv) + ldx(bb, c, inf32);
        if (OUTSEL && inf32) ((float*)o)[obase + j] = v;
        else                 ((u16*)o)[obase + j] = f2bf(v);
    }
}

// ---------------------------------------------------------------------------
extern "C" void kernel_launch(void* const* d_in, const int* in_sizes, int n_in,
                              void* d_out, int out_size, void* d_ws, size_t ws_size,
                              hipStream_t stream)
{
    const void* x     = d_in[0];
    const void* in_w  = d_in[1];
    const void* in_b  = d_in[2];
    const void* out_w = d_in[3];
    const void* out_b = d_in[4];
    const void* fc1_w = d_in[5];
    const void* fc1_b = d_in[6];
    const void* fc2_w = d_in[7];
    const void* fc2_b = d_in[8];
    const void* ln1w  = d_in[9];
    const void* ln1b  = d_in[10];
    const void* ln2w  = d_in[11];
    const void* ln2b  = d_in[12];
    const void* pad   = d_in[13];
    u16* outp = (u16*)d_out;
    char* ws = (char*)d_ws;
    dim3 blk(256);

    const size_t MB = 1024 * 1024;
    const bool bigWS = ws_size >= (105 * MB + 64 * 1024);

    if (bigWS) {
        // ---- Tier A: full-size pipeline, everything converted to bf16 ----
        u16*   xb   = (u16*)(ws + 0);
        u16*   w1b  = (u16*)(ws + 16 * MB);
        u16*   wob  = (u16*)(ws + 22 * MB);
        u16*   f1b  = (u16*)(ws + 24 * MB);
        u16*   f2b  = (u16*)(ws + 32 * MB);
        u16*   inbb = (u16*)(ws + 40 * MB);
        u16*   outbb= (u16*)(ws + 40 * MB + 8192);
        u16*   f1bb = (u16*)(ws + 40 * MB + 16384);
        u16*   f2bb = (u16*)(ws + 40 * MB + 24576);
        u16*   Ko   = (u16*)(ws + 41 * MB);
        u16*   Vo   = (u16*)(ws + 57 * MB);
        u16*   y1   = (u16*)(ws + 73 * MB);
        u16*   x1   = (u16*)(ws + 41 * MB);     // reuse Ko after attn
        u16*   hc   = (u16*)(ws + 57 * MB);     // reuse Vo in FF
        float* acc  = (float*)(ws + 73 * MB);   // 32 MB, reuse y1 in FF
        int*   flags  = (int*)(ws + 105 * MB);
        int*   flagsA = (int*)(ws + 105 * MB + 32);
        float* kbias  = (float*)(ws + 105 * MB + 64);

        probe_kernel<<<dim3(1), dim3(64), 0, stream>>>(x, pad, flags, flagsA);
        mask_to_bias<<<dim3(32), blk, 0, stream>>>(pad, kbias, flags);
        conv4<<<dim3(8192), blk, 0, stream>>>(x, xb, 2097152, flags);
        conv4<<<dim3(3072), blk, 0, stream>>>(in_w, w1b, 786432, flags);
        conv4<<<dim3(1024), blk, 0, stream>>>(out_w, wob, 262144, flags);
        conv4<<<dim3(4096), blk, 0, stream>>>(fc1_w, f1b, 1048576, flags);
        conv4<<<dim3(4096), blk, 0, stream>>>(fc2_w, f2b, 1048576, flags);
        conv4<<<dim3(3), blk, 0, stream>>>(in_b, inbb, 768, flags);
        conv4<<<dim3(1), blk, 0, stream>>>(out_b, outbb, 256, flags);
        conv4<<<dim3(4), blk, 0, stream>>>(fc1_b, f1bb, 1024, flags);
        conv4<<<dim3(1), blk, 0, stream>>>(fc2_b, f2bb, 256, flags);

        // QKV: Q (scaled) -> d_out, K/V full buffers
        gemm_qkv<<<dim3(64, 24), blk, 0, stream>>>(
            xb, 0, w1b, inbb, outp, Ko, Vo, flagsA);
        // attention full batch, in-place in d_out
        attn_kernel<<<dim3(16, 128), blk, 0, stream>>>(outp, Ko, Vo, kbias, 0);
        // y1 = O @ out_w^T + out_b + x
        gemm_bt<1><<<dim3(64, 8), blk, 0, stream>>>(
            outp, 0, 0, wob, 0, outbb, 0, xb, 0, 0, y1, 0, 1024, 1024, 1024, flagsA);
        // x1 = LN1(y1)
        ln_kernel<1, 0><<<dim3(8192), blk, 0, stream>>>(y1, ln1w, ln1b, x1, 0, flags);
        // FF full-M in 4 K-chunks, fp32 accumulation
        for (int c = 0; c < 4; c++) {
            gemm_bt<2><<<dim3(64, 8), blk, 0, stream>>>(
                x1, 0, 0, f1b, (long)c * 1024 * 1024, f1bb, (long)c * 1024,
                nullptr, 0, 0, hc, 0, 1024, 1024, 1024, flagsA);
            gemm_accf32<<<dim3(64, 8), blk, 0, stream>>>(
                hc, f2b, (long)c * 1024, f2bb, x1, 0, acc, 4096, c == 0, flagsA);
        }
        ln_kernel<0, 1><<<dim3(8192), blk, 0, stream>>>(acc, ln2w, ln2b, d_out, 0, flags);
    } else {
        // ---- Tier C: round-4 quartered structure (12.6 MB workspace) ----
        u16*   Ko    = (u16*)(ws + 0);
        u16*   Vo    = (u16*)(ws + 4 * MB);
        u16*   y1h   = (u16*)(ws + 0);
        float* acc   = (float*)(ws + 0);
        u16*   hc    = (u16*)(ws + 8 * MB);
        int*   flags  = (int*)(ws + 12 * MB);
        int*   flagsA = (int*)(ws + 12 * MB + 32);
        float* kbias  = (float*)(ws + 12 * MB + 64);

        probe_kernel<<<dim3(1), dim3(64), 0, stream>>>(x, pad, flags, flagsA);
        mask_to_bias<<<dim3(32), blk, 0, stream>>>(pad, kbias, flags);

        for (int q = 0; q < 4; q++) {
            const long r0 = (long)q * 2048;
            gemm_qkv<<<dim3(16, 24), blk, 0, stream>>>(
                x, r0, in_w, in_b, outp, Ko, Vo, flags);
            attn_kernel<<<dim3(16, 32), blk, 0, stream>>>(
                outp, Ko, Vo, kbias, q * 2);
        }
        for (int hf = 0; hf < 2; hf++) {
            const long r0 = (long)hf * 4096;
            gemm_bt<1><<<dim3(32, 8), blk, 0, stream>>>(
                outp, 0, r0, out_w, 0, out_b, 0, x, 1, r0,
                y1h, 0, 1024, 1024, 1024, flags);
            ln_kernel<1, 0><<<dim3(4096), blk, 0, stream>>>(
                y1h, ln1w, ln1b, outp, r0, flags);
        }
        for (int q = 3; q >= 0; q--) {
            const long r0 = (long)q * 2048;
            for (int c = 0; c < 4; c++) {
                gemm_bt<2><<<dim3(16, 8), blk, 0, stream>>>(
                    outp, 0, r0, fc1_w, (long)c * 1024 * 1024, fc1_b, (long)c * 1024,
                    nullptr, 0, 0, hc, 0, 1024, 1024, 1024, flags);
                gemm_accf32<<<dim3(16, 8), blk, 0, stream>>>(
                    hc, fc2_w, (long)c * 1024, fc2_b, outp, r0,
                    acc, 4096, c == 0, flags);
            }
            ln_kernel<0, 1><<<dim3(2048), blk, 0, stream>>>(
                acc, ln2w, ln2b, d_out, r0, flags);
        }
    }
}

// Round 6
// 690.120 us; speedup vs baseline: 3.5810x; 1.1904x over previous
//
#include <hip/hip_runtime.h>

typedef unsigned short u16;
typedef __attribute__((ext_vector_type(8))) short short8;
typedef __attribute__((ext_vector_type(4))) short short4v;
typedef __attribute__((ext_vector_type(4))) float f32x4;

#define DEV static __device__ __forceinline__

DEV float bf2f(u16 h) {
    union { unsigned int u; float f; } v; v.u = ((unsigned int)h) << 16; return v.f;
}
DEV u16 f2bf(float f) {
    union { float f; unsigned int u; } v; v.f = f;
    unsigned int r = (v.u + 0x7fff + ((v.u >> 16) & 1)) >> 16;
    return (u16)r;
}
DEV float ldx(const void* p, size_t i, int f32) {
    return f32 ? ((const float*)p)[i] : bf2f(((const u16*)p)[i]);
}

#define GLD16(g, l) __builtin_amdgcn_global_load_lds( \
    (const __attribute__((address_space(1))) void*)(g), \
    (__attribute__((address_space(3))) void*)(l), 16, 0, 0)

#define STAGE(P, pf32, eoff, dst8) do {                                        \
    if (!(pf32)) { GLD16(((const u16*)(P)) + (eoff), (dst8)); }                \
    else {                                                                     \
        const float* _p = ((const float*)(P)) + (eoff);                        \
        f32x4 _a = *(const f32x4*)_p, _b = *(const f32x4*)(_p + 4);            \
        short8 _s;                                                             \
        _s[0]=(short)f2bf(_a[0]); _s[1]=(short)f2bf(_a[1]);                    \
        _s[2]=(short)f2bf(_a[2]); _s[3]=(short)f2bf(_a[3]);                    \
        _s[4]=(short)f2bf(_b[0]); _s[5]=(short)f2bf(_b[1]);                    \
        _s[6]=(short)f2bf(_b[2]); _s[7]=(short)f2bf(_b[3]);                    \
        *(short8*)(dst8) = _s;                                                 \
    } } while (0)

// ---------------------------------------------------------------------------
// Probe: flags[0]=1 -> inputs fp32; flags[1]=1 -> mask is bool bytes.
// flagsA = {0,0} for already-bf16 buffers.
// ---------------------------------------------------------------------------
__global__ __launch_bounds__(64) void probe_kernel(
    const void* __restrict__ x, const void* __restrict__ pad,
    int* __restrict__ flags, int* __restrict__ flagsA)
{
    const int lane = threadIdx.x;
    const u16* xu = (const u16*)x;
    const unsigned int e = (xu[lane * 2] >> 7) & 0xFF;
    const int sane = (e >= 0x70 && e <= 0x8F) ? 1 : 0;
    unsigned long long m = __ballot(sane);
    const int f32 = (__popcll(m) < 32) ? 1 : 0;

    const unsigned int* pi = (const unsigned int*)pad;
    int bytes = 0;
#pragma unroll
    for (int j = 0; j < 6; j++) {
        unsigned int v = pi[128 + j * 64 + lane];
        if (v > 1u) bytes = 1;
    }
    m = __ballot(bytes);
    if (lane == 0) {
        flags[0] = f32; flags[1] = (m != 0ULL) ? 1 : 0;
        flagsA[0] = 0;  flagsA[1] = 0;
    }
}

__global__ __launch_bounds__(256) void conv4(
    const void* __restrict__ src, u16* __restrict__ dst, int n4,
    const int* __restrict__ flags)
{
    const int i = blockIdx.x * 256 + threadIdx.x;
    if (i >= n4) return;
    if (flags[0]) {
        f32x4 v = ((const f32x4*)src)[i];
        short4v s;
        s[0] = (short)f2bf(v[0]); s[1] = (short)f2bf(v[1]);
        s[2] = (short)f2bf(v[2]); s[3] = (short)f2bf(v[3]);
        ((short4v*)dst)[i] = s;
    } else {
        ((short4v*)dst)[i] = ((const short4v*)src)[i];
    }
}

__global__ __launch_bounds__(256) void mask_to_bias(
    const void* __restrict__ pad, float* __restrict__ out,
    const int* __restrict__ flags)
{
    const int i = blockIdx.x * 256 + threadIdx.x;
    const int mv = flags[1] ? (int)((const unsigned char*)pad)[i]
                            : ((const int*)pad)[i];
    out[i] = mv ? -1e30f : 0.0f;
}

// ---------------------------------------------------------------------------
// Shared GEMM core: 128x128 tile, BK=32, 256 threads (4 waves, 4x4 mfma each).
// ---------------------------------------------------------------------------
#define GEMM_CORE(Av, ASEL, a_row0, Wv, w_off, ldw, K)                        \
    __shared__ __align__(16) u16 As[128 * 32];                                \
    __shared__ __align__(16) u16 Bs[128 * 32];                                \
    const int inf32 = flags[0];                                               \
    const int af32  = (ASEL) ? inf32 : 0;                                     \
    const int tid  = threadIdx.x;                                             \
    const int lane = tid & 63;                                                \
    const int wave = tid >> 6;                                                \
    const int lc   = lane & 15;                                               \
    const int quad = lane >> 4;                                               \
    const int m0 = blockIdx.x * 128;                                          \
    const int n0 = blockIdx.y * 128;                                          \
    const int wm = (wave >> 1) * 64;                                          \
    const int wn = (wave & 1) * 64;                                           \
    const int r0 = tid >> 2;                                                  \
    const int ko = (tid & 3) * 8;                                             \
    f32x4 acc[4][4] = {};                                                     \
    for (int k0 = 0; k0 < (K); k0 += 32) {                                    \
        STAGE(Av, af32, ((size_t)(a_row0) + m0 + r0) * (K) + k0 + ko,         \
              &As[tid * 8]);                                                  \
        STAGE(Av, af32, ((size_t)(a_row0) + m0 + r0 + 64) * (K) + k0 + ko,    \
              &As[2048 + tid * 8]);                                           \
        STAGE(Wv, inf32, (size_t)(w_off) + (size_t)(n0 + r0) * (ldw) + k0 + ko,\
              &Bs[tid * 8]);                                                  \
        STAGE(Wv, inf32, (size_t)(w_off) + (size_t)(n0 + r0 + 64) * (ldw) + k0 + ko,\
              &Bs[2048 + tid * 8]);                                           \
        __syncthreads();                                                      \
        short8 afr[4], bfr[4];                                                \
        const int qd = quad * 8;                                              \
        _Pragma("unroll")                                                     \
        for (int mt = 0; mt < 4; mt++)                                        \
            afr[mt] = *(const short8*)&As[(wm + mt * 16 + lc) * 32 + qd];     \
        _Pragma("unroll")                                                     \
        for (int nt = 0; nt < 4; nt++)                                        \
            bfr[nt] = *(const short8*)&Bs[(wn + nt * 16 + lc) * 32 + qd];     \
        _Pragma("unroll")                                                     \
        for (int mt = 0; mt < 4; mt++)                                        \
            _Pragma("unroll")                                                 \
            for (int nt = 0; nt < 4; nt++)                                    \
                acc[mt][nt] = __builtin_amdgcn_mfma_f32_16x16x32_bf16(        \
                    afr[mt], bfr[nt], acc[mt][nt], 0, 0, 0);                  \
        __syncthreads();                                                      \
    }                                                                         \
    const int ce0 = n0 + wn + lc;                                             \
    const int re0 = m0 + wm + quad * 4;

// Generic GEMM: C = A @ W^T + bias.  EPI: 0 bias, 1 +resid, 2 +relu.
template<int EPI>
__global__ __launch_bounds__(256, 2) void gemm_bt(
    const void* __restrict__ A, int a_sel, long a_row0,
    const void* __restrict__ W, long w_off,
    const void* __restrict__ bias, long b_off,
    const void* __restrict__ resid, int r_sel, long r_row0,
    u16* __restrict__ C, long c_row0,
    int N, int K, int ldw, const int* __restrict__ flags)
{
    GEMM_CORE(A, a_sel, a_row0, W, w_off, ldw, K)
    const int rf32 = r_sel ? inf32 : 0;
#pragma unroll
    for (int mt = 0; mt < 4; mt++) {
#pragma unroll
        for (int nt = 0; nt < 4; nt++) {
            const int c = ce0 + nt * 16;
            const float bv = ldx(bias, (size_t)b_off + c, inf32);
#pragma unroll
            for (int i = 0; i < 4; i++) {
                const int r = re0 + mt * 16 + i;
                float v = acc[mt][nt][i] + bv;
                if (EPI == 1)
                    v += ldx(resid, ((size_t)r_row0 + r) * N + c, rf32);
                if (EPI == 2) v = fmaxf(v, 0.0f);
                C[((size_t)c_row0 + r) * N + c] = f2bf(v);
            }
        }
    }
}

// QKV GEMM (N=3072): Q (scaled 1/8) -> global rows of Qo (row-major);
// K -> local rows row-major; V -> local Vt[bh_local][64][1024] (transposed).
__global__ __launch_bounds__(256, 2) void gemm_qkv(
    const void* __restrict__ A, long a_row0,
    const void* __restrict__ W, const void* __restrict__ bias,
    u16* __restrict__ Qo, u16* __restrict__ Ko, u16* __restrict__ Vt,
    const int* __restrict__ flags)
{
    GEMM_CORE(A, 1, a_row0, W, 0, 1024, 1024)
    // n0 is 128-aligned; the three 1024-wide segments -> block-uniform branch
    if (n0 < 1024) {
#pragma unroll
        for (int mt = 0; mt < 4; mt++)
#pragma unroll
            for (int nt = 0; nt < 4; nt++) {
                const int c = ce0 + nt * 16;
                const float bv = ldx(bias, c, inf32);
#pragma unroll
                for (int i = 0; i < 4; i++) {
                    const int r = re0 + mt * 16 + i;
                    Qo[((size_t)a_row0 + r) * 1024 + c] =
                        f2bf((acc[mt][nt][i] + bv) * 0.125f);
                }
            }
    } else if (n0 < 2048) {
#pragma unroll
        for (int mt = 0; mt < 4; mt++)
#pragma unroll
            for (int nt = 0; nt < 4; nt++) {
                const int c = ce0 + nt * 16;
                const float bv = ldx(bias, c, inf32);
#pragma unroll
                for (int i = 0; i < 4; i++) {
                    const int r = re0 + mt * 16 + i;
                    Ko[(size_t)r * 1024 + (c - 1024)] = f2bf(acc[mt][nt][i] + bv);
                }
            }
    } else {
#pragma unroll
        for (int mt = 0; mt < 4; mt++)
#pragma unroll
            for (int nt = 0; nt < 4; nt++) {
                const int c = ce0 + nt * 16;
                const float bv = ldx(bias, c, inf32);
                const int cv = c - 2048;
                const int hh = cv >> 6, d = cv & 63;
                const int rb = re0 + mt * 16;       // 4-aligned, block within 1 seq
                const int bl = rb >> 10, t = rb & 1023;
                short4v pk;
#pragma unroll
                for (int i = 0; i < 4; i++)
                    pk[i] = (short)f2bf(acc[mt][nt][i] + bv);
                *(short4v*)&Vt[((size_t)(bl * 16 + hh) * 64 + d) * 1024 + t] = pk;
            }
    }
}

// fc2 K-chunk accumulating into fp32 (tier C only)
__global__ __launch_bounds__(256, 2) void gemm_accf32(
    const void* __restrict__ A, const void* __restrict__ W, long w_off,
    const void* __restrict__ bias, const u16* __restrict__ resid, long r_row0,
    float* __restrict__ C, int ldw, int init, const int* __restrict__ flags)
{
    GEMM_CORE(A, 0, 0, W, w_off, ldw, 1024)
#pragma unroll
    for (int mt = 0; mt < 4; mt++) {
#pragma unroll
        for (int nt = 0; nt < 4; nt++) {
            const int c = ce0 + nt * 16;
            const float bv = ldx(bias, c, inf32);
#pragma unroll
            for (int i = 0; i < 4; i++) {
                const int r = re0 + mt * 16 + i;
                float v = acc[mt][nt][i];
                if (init) v += bv + bf2f(resid[((size_t)r_row0 + r) * 1024 + c]);
                else      v += C[(size_t)r * 1024 + c];
                C[(size_t)r * 1024 + c] = v;
            }
        }
    }
}

// fc2 full-K (tier A): y2[r][c] = A[a_row0+r,:4096] @ W[c,:4096]^T + b + resid
__global__ __launch_bounds__(256, 2) void gemm_f32out(
    const void* __restrict__ A, long a_row0,
    const void* __restrict__ W, const void* __restrict__ bias,
    const u16* __restrict__ resid, float* __restrict__ C,
    const int* __restrict__ flags)
{
    GEMM_CORE(A, 0, a_row0, W, 0, 4096, 4096)
#pragma unroll
    for (int mt = 0; mt < 4; mt++) {
#pragma unroll
        for (int nt = 0; nt < 4; nt++) {
            const int c = ce0 + nt * 16;
            const float bv = bf2f(((const u16*)bias)[c]);
#pragma unroll
            for (int i = 0; i < 4; i++) {
                const int r = re0 + mt * 16 + i;
                C[(size_t)r * 1024 + c] = acc[mt][nt][i] + bv +
                    bf2f(resid[((size_t)a_row0 + r) * 1024 + c]);
            }
        }
    }
}

// ---------------------------------------------------------------------------
// Flash attention v2: 128 q-rows/block, in-place Q->O in QO (global rows).
// K from Ko (row-major local), V from Vt (pre-transposed [bh][d][t] local).
// All staging via global_load_lds into [kc][row][32] panels. 4 waves; wave w
// owns q-rows [w*32, w*32+32) as 2 m-tiles.
// ---------------------------------------------------------------------------
__global__ __launch_bounds__(256, 2) void attn_kernel(
    u16* __restrict__ QO, const u16* __restrict__ Ko,
    const u16* __restrict__ Vt, const float* __restrict__ kb, int b0)
{
    __shared__ __align__(16) u16 Qs[2 * 128 * 32];   // [kcd][qrow][32]
    __shared__ __align__(16) u16 Ks[2 * 64 * 32];    // [kcd][key][32]
    __shared__ __align__(16) u16 Vs[2 * 64 * 32];    // [kck][d][32]
    __shared__ __align__(16) u16 Ps[4][32 * 72];     // per-wave, stride 72
    __shared__ float kbias[64];

    const int tid  = threadIdx.x;
    const int lane = tid & 63;
    const int w    = tid >> 6;
    const int lc   = lane & 15;
    const int quad = lane >> 4;
    const int qt = blockIdx.x;            // 128-row q tile
    const int bl = blockIdx.y >> 4;       // local batch
    const int h  = blockIdx.y & 15;
    const int b  = b0 + bl;

    // stage Q: panels [kcd][128][32]
#pragma unroll
    for (int it = 0; it < 4; it++) {
        const int kcd = it >> 1, half = it & 1;
        const int r = half * 64 + (tid >> 2);
        const int c = kcd * 32 + (tid & 3) * 8;
        GLD16(&QO[((size_t)(b * 1024 + qt * 128 + r)) * 1024 + h * 64 + c],
              &Qs[kcd * 4096 + half * 2048 + tid * 8]);
    }
    __syncthreads();

    short8 aq[2][2];
#pragma unroll
    for (int mt = 0; mt < 2; mt++)
#pragma unroll
        for (int kc = 0; kc < 2; kc++)
            aq[mt][kc] = *(const short8*)
                &Qs[kc * 4096 + (w * 32 + mt * 16 + lc) * 32 + quad * 8];

    f32x4 o[2][4] = {};
    float m_i[2][4], l_i[2][4];
#pragma unroll
    for (int mt = 0; mt < 2; mt++)
#pragma unroll
        for (int i = 0; i < 4; i++) { m_i[mt][i] = -1e30f; l_i[mt][i] = 0.0f; }

    const int ktmax = 2 * qt + 2;
    for (int kt = 0; kt < ktmax; kt++) {
        __syncthreads();     // prior iter's K/V LDS reads complete
#pragma unroll
        for (int it = 0; it < 2; it++) {
            const int rr = tid >> 2;
            const int cc = it * 32 + (tid & 3) * 8;
            GLD16(&Ko[((size_t)(bl * 1024 + kt * 64 + rr)) * 1024 + h * 64 + cc],
                  &Ks[it * 2048 + tid * 8]);
            GLD16(&Vt[((size_t)(bl * 16 + h) * 64 + rr) * 1024 + kt * 64 + cc],
                  &Vs[it * 2048 + tid * 8]);
        }
        if (tid < 64)
            kbias[tid] = kb[b * 1024 + kt * 64 + tid];
        __syncthreads();

        // S = Q K^T
        short8 bk[4][2];
#pragma unroll
        for (int nt = 0; nt < 4; nt++)
#pragma unroll
            for (int kc = 0; kc < 2; kc++)
                bk[nt][kc] = *(const short8*)
                    &Ks[kc * 2048 + (nt * 16 + lc) * 32 + quad * 8];

        f32x4 s[2][4];
#pragma unroll
        for (int mt = 0; mt < 2; mt++)
#pragma unroll
            for (int nt = 0; nt < 4; nt++) {
                f32x4 z = {};
#pragma unroll
                for (int kc = 0; kc < 2; kc++)
                    z = __builtin_amdgcn_mfma_f32_16x16x32_bf16(
                        aq[mt][kc], bk[nt][kc], z, 0, 0, 0);
                s[mt][nt] = z;
            }

        float al[2][4];
#pragma unroll
        for (int mt = 0; mt < 2; mt++) {
            const int qg0 = qt * 128 + w * 32 + mt * 16 + quad * 4;
#pragma unroll
            for (int nt = 0; nt < 4; nt++) {
                const int kg = kt * 64 + nt * 16 + lc;
                const float kbv = kbias[nt * 16 + lc];
#pragma unroll
                for (int i = 0; i < 4; i++) {
                    float sv = s[mt][nt][i] + kbv;
                    if (kg > qg0 + i) sv = -1e30f;
                    s[mt][nt][i] = sv;
                }
            }
            float mnew[4], rs[4];
#pragma unroll
            for (int i = 0; i < 4; i++) {
                float rm = fmaxf(fmaxf(s[mt][0][i], s[mt][1][i]),
                                 fmaxf(s[mt][2][i], s[mt][3][i]));
                rm = fmaxf(rm, __shfl_xor(rm, 1));
                rm = fmaxf(rm, __shfl_xor(rm, 2));
                rm = fmaxf(rm, __shfl_xor(rm, 4));
                rm = fmaxf(rm, __shfl_xor(rm, 8));
                mnew[i] = fmaxf(m_i[mt][i], rm);
                al[mt][i] = exp2f((m_i[mt][i] - mnew[i]) * 1.442695041f);
                rs[i] = 0.0f;
            }
#pragma unroll
            for (int nt = 0; nt < 4; nt++)
#pragma unroll
                for (int i = 0; i < 4; i++) {
                    float p = exp2f((s[mt][nt][i] - mnew[i]) * 1.442695041f);
                    s[mt][nt][i] = p;
                    rs[i] += p;
                }
#pragma unroll
            for (int i = 0; i < 4; i++) {
                float r = rs[i];
                r += __shfl_xor(r, 1);
                r += __shfl_xor(r, 2);
                r += __shfl_xor(r, 4);
                r += __shfl_xor(r, 8);
                l_i[mt][i] = l_i[mt][i] * al[mt][i] + r;
                m_i[mt][i] = mnew[i];
            }
            // P -> wave-private LDS strip (stride 72)
#pragma unroll
            for (int nt = 0; nt < 4; nt++)
#pragma unroll
                for (int i = 0; i < 4; i++)
                    Ps[w][(mt * 16 + quad * 4 + i) * 72 + nt * 16 + lc] =
                        f2bf(s[mt][nt][i]);
        }

        // O = O*alpha + P @ V
        short8 ap[2][2], bv[4][2];
#pragma unroll
        for (int mt = 0; mt < 2; mt++)
#pragma unroll
            for (int kc = 0; kc < 2; kc++)
                ap[mt][kc] = *(const short8*)
                    &Ps[w][(mt * 16 + lc) * 72 + kc * 32 + quad * 8];
#pragma unroll
        for (int nt = 0; nt < 4; nt++)
#pragma unroll
            for (int kc = 0; kc < 2; kc++)
                bv[nt][kc] = *(const short8*)
                    &Vs[kc * 2048 + (nt * 16 + lc) * 32 + quad * 8];
#pragma unroll
        for (int mt = 0; mt < 2; mt++)
#pragma unroll
            for (int nt = 0; nt < 4; nt++) {
                f32x4 oo = o[mt][nt];
#pragma unroll
                for (int i = 0; i < 4; i++) oo[i] *= al[mt][i];
#pragma unroll
                for (int kc = 0; kc < 2; kc++)
                    oo = __builtin_amdgcn_mfma_f32_16x16x32_bf16(
                        ap[mt][kc], bv[nt][kc], oo, 0, 0, 0);
                o[mt][nt] = oo;
            }
    }

    // write O in place of Q
#pragma unroll
    for (int mt = 0; mt < 2; mt++)
#pragma unroll
        for (int i = 0; i < 4; i++) {
            const float inv = l_i[mt][i] > 0.0f ? 1.0f / l_i[mt][i] : 0.0f;
#pragma unroll
            for (int nt = 0; nt < 4; nt++) {
                const int r = qt * 128 + w * 32 + mt * 16 + quad * 4 + i;
                const int d = nt * 16 + lc;
                QO[((size_t)(b * 1024 + r)) * 1024 + h * 64 + d] =
                    f2bf(o[mt][nt][i] * inv);
            }
        }
}

// ---------------------------------------------------------------------------
// LayerNorm, one block/row, biased variance, eps=1e-12.
// ---------------------------------------------------------------------------
template<int IN16, int OUTSEL>
__global__ __launch_bounds__(256) void ln_kernel(
    const void* __restrict__ yv, const void* __restrict__ w,
    const void* __restrict__ bb, void* __restrict__ o, long o_row0,
    const int* __restrict__ flags)
{
    const int row = blockIdx.x;
    const int tid = threadIdx.x;
    const int inf32 = flags[0];
    float x0, x1, x2, x3;
    if (IN16) {
        const u16* p = (const u16*)yv + (size_t)row * 1024 + tid * 4;
        short4v v = *(const short4v*)p;
        x0 = bf2f((u16)v[0]); x1 = bf2f((u16)v[1]);
        x2 = bf2f((u16)v[2]); x3 = bf2f((u16)v[3]);
    } else {
        const float* p = (const float*)yv + (size_t)row * 1024 + tid * 4;
        f32x4 v = *(const f32x4*)p;
        x0 = v[0]; x1 = v[1]; x2 = v[2]; x3 = v[3];
    }
    float s = x0 + x1 + x2 + x3;
    float q = x0 * x0 + x1 * x1 + x2 * x2 + x3 * x3;
#pragma unroll
    for (int off = 32; off; off >>= 1) {
        s += __shfl_xor(s, off);
        q += __shfl_xor(q, off);
    }
    __shared__ float sm[8];
    const int lane = tid & 63, wv = tid >> 6;
    if (lane == 0) { sm[wv] = s; sm[4 + wv] = q; }
    __syncthreads();
    const float ts = sm[0] + sm[1] + sm[2] + sm[3];
    const float tq = sm[4] + sm[5] + sm[6] + sm[7];
    const float mean = ts * (1.0f / 1024.0f);
    float var = tq * (1.0f / 1024.0f) - mean * mean;
    if (var < 0.0f) var = 0.0f;
    const float rinv = rsqrtf(var + 1e-12f);

    const size_t obase = ((size_t)o_row0 + row) * 1024 + tid * 4;
#pragma unroll
    for (int j = 0; j < 4; j++) {
        const int c = tid * 4 + j;
        float xv = (j == 0) ? x0 : (j == 1) ? x1 : (j == 2) ? x2 : x3;
        float v = ldx(w, c, inf32) * ((xv - mean) * rinv) + ldx(bb, c, inf32);
        if (OUTSEL && inf32) ((float*)o)[obase + j] = v;
        else                 ((u16*)o)[obase + j] = f2bf(v);
    }
}

// ---------------------------------------------------------------------------
extern "C" void kernel_launch(void* const* d_in, const int* in_sizes, int n_in,
                              void* d_out, int out_size, void* d_ws, size_t ws_size,
                              hipStream_t stream)
{
    const void* x     = d_in[0];
    const void* in_w  = d_in[1];
    const void* in_b  = d_in[2];
    const void* out_w = d_in[3];
    const void* out_b = d_in[4];
    const void* fc1_w = d_in[5];
    const void* fc1_b = d_in[6];
    const void* fc2_w = d_in[7];
    const void* fc2_b = d_in[8];
    const void* ln1w  = d_in[9];
    const void* ln1b  = d_in[10];
    const void* ln2w  = d_in[11];
    const void* ln2b  = d_in[12];
    const void* pad   = d_in[13];
    u16* outp = (u16*)d_out;
    char* ws = (char*)d_ws;
    dim3 blk(256);

    const size_t MB = 1024 * 1024;
    const bool bigWS = ws_size >= (105 * MB + 64 * 1024);

    if (bigWS) {
        // Tier A layout:
        //  0-16  xb (then x1 after out-proj)     16-22 w1b   22-24 wob
        //  24-32 f1b   32-40 f2b   40+ biases    41-57 Ko    57-73 Vt
        //  73-89 y1    41-105 h (FF phase)       16-32 y2h (FF phase)
        //  105+ flags / kbias
        u16*   xb   = (u16*)(ws + 0);
        u16*   x1   = (u16*)(ws + 0);
        u16*   w1b  = (u16*)(ws + 16 * MB);
        u16*   wob  = (u16*)(ws + 22 * MB);
        u16*   f1b  = (u16*)(ws + 24 * MB);
        u16*   f2b  = (u16*)(ws + 32 * MB);
        u16*   inbb = (u16*)(ws + 40 * MB);
        u16*   outbb= (u16*)(ws + 40 * MB + 8192);
        u16*   f1bb = (u16*)(ws + 40 * MB + 16384);
        u16*   f2bb = (u16*)(ws + 40 * MB + 24576);
        u16*   Ko   = (u16*)(ws + 41 * MB);
        u16*   Vt   = (u16*)(ws + 57 * MB);
        u16*   y1   = (u16*)(ws + 73 * MB);
        u16*   h    = (u16*)(ws + 41 * MB);
        float* y2h  = (float*)(ws + 16 * MB);
        int*   flags  = (int*)(ws + 105 * MB);
        int*   flagsA = (int*)(ws + 105 * MB + 32);
        float* kbias  = (float*)(ws + 105 * MB + 64);

        probe_kernel<<<dim3(1), dim3(64), 0, stream>>>(x, pad, flags, flagsA);
        mask_to_bias<<<dim3(32), blk, 0, stream>>>(pad, kbias, flags);
        conv4<<<dim3(8192), blk, 0, stream>>>(x, xb, 2097152, flags);
        conv4<<<dim3(3072), blk, 0, stream>>>(in_w, w1b, 786432, flags);
        conv4<<<dim3(1024), blk, 0, stream>>>(out_w, wob, 262144, flags);
        conv4<<<dim3(4096), blk, 0, stream>>>(fc1_w, f1b, 1048576, flags);
        conv4<<<dim3(4096), blk, 0, stream>>>(fc2_w, f2b, 1048576, flags);
        conv4<<<dim3(3), blk, 0, stream>>>(in_b, inbb, 768, flags);
        conv4<<<dim3(1), blk, 0, stream>>>(out_b, outbb, 256, flags);
        conv4<<<dim3(4), blk, 0, stream>>>(fc1_b, f1bb, 1024, flags);
        conv4<<<dim3(1), blk, 0, stream>>>(fc2_b, f2bb, 256, flags);

        gemm_qkv<<<dim3(64, 24), blk, 0, stream>>>(
            xb, 0, w1b, inbb, outp, Ko, Vt, flagsA);
        attn_kernel<<<dim3(8, 128), blk, 0, stream>>>(outp, Ko, Vt, kbias, 0);
        gemm_bt<1><<<dim3(64, 8), blk, 0, stream>>>(
            outp, 0, 0, wob, 0, outbb, 0, xb, 0, 0, y1, 0, 1024, 1024, 1024, flagsA);
        ln_kernel<1, 0><<<dim3(8192), blk, 0, stream>>>(y1, ln1w, ln1b, x1, 0, flags);
        // fc1 full: h = relu(x1 @ f1b^T + f1bb)   [8192, 4096]
        gemm_bt<2><<<dim3(64, 32), blk, 0, stream>>>(
            x1, 0, 0, f1b, 0, f1bb, 0, nullptr, 0, 0, h, 0, 4096, 1024, 1024, flagsA);
        // fc2 full-K per half + LN2
        for (int hf = 0; hf < 2; hf++) {
            const long r0 = (long)hf * 4096;
            gemm_f32out<<<dim3(32, 8), blk, 0, stream>>>(
                h, r0, f2b, f2bb, x1, y2h, flagsA);
            ln_kernel<0, 1><<<dim3(4096), blk, 0, stream>>>(
                y2h, ln2w, ln2b, d_out, r0, flags);
        }
    } else {
        // Tier C: quartered, 12.6 MB workspace
        u16*   Ko    = (u16*)(ws + 0);
        u16*   Vt    = (u16*)(ws + 4 * MB);
        u16*   y1h   = (u16*)(ws + 0);
        float* acc   = (float*)(ws + 0);
        u16*   hc    = (u16*)(ws + 8 * MB);
        int*   flags  = (int*)(ws + 12 * MB);
        int*   flagsA = (int*)(ws + 12 * MB + 32);
        float* kbias  = (float*)(ws + 12 * MB + 64);

        probe_kernel<<<dim3(1), dim3(64), 0, stream>>>(x, pad, flags, flagsA);
        mask_to_bias<<<dim3(32), blk, 0, stream>>>(pad, kbias, flags);

        for (int q = 0; q < 4; q++) {
            const long r0 = (long)q * 2048;
            gemm_qkv<<<dim3(16, 24), blk, 0, stream>>>(
                x, r0, in_w, in_b, outp, Ko, Vt, flags);
            attn_kernel<<<dim3(8, 32), blk, 0, stream>>>(
                outp, Ko, Vt, kbias, q * 2);
        }
        for (int hf = 0; hf < 2; hf++) {
            const long r0 = (long)hf * 4096;
            gemm_bt<1><<<dim3(32, 8), blk, 0, stream>>>(
                outp, 0, r0, out_w, 0, out_b, 0, x, 1, r0,
                y1h, 0, 1024, 1024, 1024, flags);
            ln_kernel<1, 0><<<dim3(4096), blk, 0, stream>>>(
                y1h, ln1w, ln1b, outp, r0, flags);
        }
        for (int q = 3; q >= 0; q--) {
            const long r0 = (long)q * 2048;
            for (int c = 0; c < 4; c++) {
                gemm_bt<2><<<dim3(16, 8), blk, 0, stream>>>(
                    outp, 0, r0, fc1_w, (long)c * 1024 * 1024, fc1_b, (long)c * 1024,
                    nullptr, 0, 0, hc, 0, 1024, 1024, 1024, flags);
                gemm_accf32<<<dim3(16, 8), blk, 0, stream>>>(
                    hc, fc2_w, (long)c * 1024, fc2_b, outp, r0,
                    acc, 4096, c == 0, flags);
            }
            ln_kernel<0, 1><<<dim3(2048), blk, 0, stream>>>(
                acc, ln2w, ln2b, d_out, r0, flags);
        }
    }
}

// Round 7
// 602.793 us; speedup vs baseline: 4.0997x; 1.1449x over previous
//
#include <hip/hip_runtime.h>

typedef unsigned short u16;
typedef __attribute__((ext_vector_type(8))) short short8;
typedef __attribute__((ext_vector_type(4))) short short4v;
typedef __attribute__((ext_vector_type(4))) float f32x4;

#define DEV static __device__ __forceinline__

DEV float bf2f(u16 h) {
    union { unsigned int u; float f; } v; v.u = ((unsigned int)h) << 16; return v.f;
}
DEV u16 f2bf(float f) {
    union { float f; unsigned int u; } v; v.f = f;
    unsigned int r = (v.u + 0x7fff + ((v.u >> 16) & 1)) >> 16;
    return (u16)r;
}
DEV float ldx(const void* p, size_t i, int f32) {
    return f32 ? ((const float*)p)[i] : bf2f(((const u16*)p)[i]);
}

#define GLD16(g, l) __builtin_amdgcn_global_load_lds( \
    (const __attribute__((address_space(1))) void*)(g), \
    (__attribute__((address_space(3))) void*)(l), 16, 0, 0)

#define STAGE(P, pf32, eoff, dst8) do {                                        \
    if (!(pf32)) { GLD16(((const u16*)(P)) + (eoff), (dst8)); }                \
    else {                                                                     \
        const float* _p = ((const float*)(P)) + (eoff);                        \
        f32x4 _a = *(const f32x4*)_p, _b = *(const f32x4*)(_p + 4);            \
        short8 _s;                                                             \
        _s[0]=(short)f2bf(_a[0]); _s[1]=(short)f2bf(_a[1]);                    \
        _s[2]=(short)f2bf(_a[2]); _s[3]=(short)f2bf(_a[3]);                    \
        _s[4]=(short)f2bf(_b[0]); _s[5]=(short)f2bf(_b[1]);                    \
        _s[6]=(short)f2bf(_b[2]); _s[7]=(short)f2bf(_b[3]);                    \
        *(short8*)(dst8) = _s;                                                 \
    } } while (0)

// ---------------------------------------------------------------------------
// Probe: flags[0]=1 -> inputs fp32; flags[1]=1 -> mask is bool bytes.
// ---------------------------------------------------------------------------
__global__ __launch_bounds__(64) void probe_kernel(
    const void* __restrict__ x, const void* __restrict__ pad,
    int* __restrict__ flags, int* __restrict__ flagsA)
{
    const int lane = threadIdx.x;
    const u16* xu = (const u16*)x;
    const unsigned int e = (xu[lane * 2] >> 7) & 0xFF;
    const int sane = (e >= 0x70 && e <= 0x8F) ? 1 : 0;
    unsigned long long m = __ballot(sane);
    const int f32 = (__popcll(m) < 32) ? 1 : 0;

    const unsigned int* pi = (const unsigned int*)pad;
    int bytes = 0;
#pragma unroll
    for (int j = 0; j < 6; j++) {
        unsigned int v = pi[128 + j * 64 + lane];
        if (v > 1u) bytes = 1;
    }
    m = __ballot(bytes);
    if (lane == 0) {
        flags[0] = f32; flags[1] = (m != 0ULL) ? 1 : 0;
        flagsA[0] = 0;  flagsA[1] = 0;
    }
}

__global__ __launch_bounds__(256) void conv4(
    const void* __restrict__ src, u16* __restrict__ dst, int n4,
    const int* __restrict__ flags)
{
    const int i = blockIdx.x * 256 + threadIdx.x;
    if (i >= n4) return;
    if (flags[0]) {
        f32x4 v = ((const f32x4*)src)[i];
        short4v s;
        s[0] = (short)f2bf(v[0]); s[1] = (short)f2bf(v[1]);
        s[2] = (short)f2bf(v[2]); s[3] = (short)f2bf(v[3]);
        ((short4v*)dst)[i] = s;
    } else {
        ((short4v*)dst)[i] = ((const short4v*)src)[i];
    }
}

__global__ __launch_bounds__(256) void mask_to_bias(
    const void* __restrict__ pad, float* __restrict__ out,
    const int* __restrict__ flags)
{
    const int i = blockIdx.x * 256 + threadIdx.x;
    const int mv = flags[1] ? (int)((const unsigned char*)pad)[i]
                            : ((const int*)pad)[i];
    out[i] = mv ? -1e30f : 0.0f;
}

// ---------------------------------------------------------------------------
// Shared GEMM core: 128x128 tile, BK=32, 256 threads (4 waves, 4x4 mfma each).
// ---------------------------------------------------------------------------
#define GEMM_CORE(Av, ASEL, a_row0, Wv, w_off, ldw, K)                        \
    __shared__ __align__(16) u16 As[128 * 32];                                \
    __shared__ __align__(16) u16 Bs[128 * 32];                                \
    const int inf32 = flags[0];                                               \
    const int af32  = (ASEL) ? inf32 : 0;                                     \
    const int tid  = threadIdx.x;                                             \
    const int lane = tid & 63;                                                \
    const int wave = tid >> 6;                                                \
    const int lc   = lane & 15;                                               \
    const int quad = lane >> 4;                                               \
    const int m0 = blockIdx.x * 128;                                          \
    const int n0 = blockIdx.y * 128;                                          \
    const int wm = (wave >> 1) * 64;                                          \
    const int wn = (wave & 1) * 64;                                           \
    const int r0 = tid >> 2;                                                  \
    const int ko = (tid & 3) * 8;                                             \
    f32x4 acc[4][4] = {};                                                     \
    for (int k0 = 0; k0 < (K); k0 += 32) {                                    \
        STAGE(Av, af32, ((size_t)(a_row0) + m0 + r0) * (K) + k0 + ko,         \
              &As[tid * 8]);                                                  \
        STAGE(Av, af32, ((size_t)(a_row0) + m0 + r0 + 64) * (K) + k0 + ko,    \
              &As[2048 + tid * 8]);                                           \
        STAGE(Wv, inf32, (size_t)(w_off) + (size_t)(n0 + r0) * (ldw) + k0 + ko,\
              &Bs[tid * 8]);                                                  \
        STAGE(Wv, inf32, (size_t)(w_off) + (size_t)(n0 + r0 + 64) * (ldw) + k0 + ko,\
              &Bs[2048 + tid * 8]);                                           \
        __syncthreads();                                                      \
        short8 afr[4], bfr[4];                                                \
        const int qd = quad * 8;                                              \
        _Pragma("unroll")                                                     \
        for (int mt = 0; mt < 4; mt++)                                        \
            afr[mt] = *(const short8*)&As[(wm + mt * 16 + lc) * 32 + qd];     \
        _Pragma("unroll")                                                     \
        for (int nt = 0; nt < 4; nt++)                                        \
            bfr[nt] = *(const short8*)&Bs[(wn + nt * 16 + lc) * 32 + qd];     \
        _Pragma("unroll")                                                     \
        for (int mt = 0; mt < 4; mt++)                                        \
            _Pragma("unroll")                                                 \
            for (int nt = 0; nt < 4; nt++)                                    \
                acc[mt][nt] = __builtin_amdgcn_mfma_f32_16x16x32_bf16(        \
                    afr[mt], bfr[nt], acc[mt][nt], 0, 0, 0);                  \
        __syncthreads();                                                      \
    }                                                                         \
    const int ce0 = n0 + wn + lc;                                             \
    const int re0 = m0 + wm + quad * 4;

// Generic GEMM: C = A @ W^T + bias.  EPI: 0 bias, 1 +resid, 2 +relu.
template<int EPI>
__global__ __launch_bounds__(256, 2) void gemm_bt(
    const void* __restrict__ A, int a_sel, long a_row0,
    const void* __restrict__ W, long w_off,
    const void* __restrict__ bias, long b_off,
    const void* __restrict__ resid, int r_sel, long r_row0,
    u16* __restrict__ C, long c_row0,
    int N, int K, int ldw, const int* __restrict__ flags)
{
    GEMM_CORE(A, a_sel, a_row0, W, w_off, ldw, K)
    const int rf32 = r_sel ? inf32 : 0;
#pragma unroll
    for (int mt = 0; mt < 4; mt++) {
#pragma unroll
        for (int nt = 0; nt < 4; nt++) {
            const int c = ce0 + nt * 16;
            const float bv = ldx(bias, (size_t)b_off + c, inf32);
#pragma unroll
            for (int i = 0; i < 4; i++) {
                const int r = re0 + mt * 16 + i;
                float v = acc[mt][nt][i] + bv;
                if (EPI == 1)
                    v += ldx(resid, ((size_t)r_row0 + r) * N + c, rf32);
                if (EPI == 2) v = fmaxf(v, 0.0f);
                C[((size_t)c_row0 + r) * N + c] = f2bf(v);
            }
        }
    }
}

// QKV GEMM (N=3072): Q (scaled 1/8) -> global rows of Qo (row-major);
// K -> local rows row-major; V -> local Vt[bh_local][64][1024] (transposed).
__global__ __launch_bounds__(256, 2) void gemm_qkv(
    const void* __restrict__ A, long a_row0,
    const void* __restrict__ W, const void* __restrict__ bias,
    u16* __restrict__ Qo, u16* __restrict__ Ko, u16* __restrict__ Vt,
    const int* __restrict__ flags)
{
    GEMM_CORE(A, 1, a_row0, W, 0, 1024, 1024)
    if (n0 < 1024) {
#pragma unroll
        for (int mt = 0; mt < 4; mt++)
#pragma unroll
            for (int nt = 0; nt < 4; nt++) {
                const int c = ce0 + nt * 16;
                const float bv = ldx(bias, c, inf32);
#pragma unroll
                for (int i = 0; i < 4; i++) {
                    const int r = re0 + mt * 16 + i;
                    Qo[((size_t)a_row0 + r) * 1024 + c] =
                        f2bf((acc[mt][nt][i] + bv) * 0.125f);
                }
            }
    } else if (n0 < 2048) {
#pragma unroll
        for (int mt = 0; mt < 4; mt++)
#pragma unroll
            for (int nt = 0; nt < 4; nt++) {
                const int c = ce0 + nt * 16;
                const float bv = ldx(bias, c, inf32);
#pragma unroll
                for (int i = 0; i < 4; i++) {
                    const int r = re0 + mt * 16 + i;
                    Ko[(size_t)r * 1024 + (c - 1024)] = f2bf(acc[mt][nt][i] + bv);
                }
            }
    } else {
#pragma unroll
        for (int mt = 0; mt < 4; mt++)
#pragma unroll
            for (int nt = 0; nt < 4; nt++) {
                const int c = ce0 + nt * 16;
                const float bv = ldx(bias, c, inf32);
                const int cv = c - 2048;
                const int hh = cv >> 6, d = cv & 63;
                const int rb = re0 + mt * 16;
                const int bl = rb >> 10, t = rb & 1023;
                short4v pk;
#pragma unroll
                for (int i = 0; i < 4; i++)
                    pk[i] = (short)f2bf(acc[mt][nt][i] + bv);
                *(short4v*)&Vt[((size_t)(bl * 16 + hh) * 64 + d) * 1024 + t] = pk;
            }
    }
}

// fc2 K-chunk accumulating into fp32 (tier C only)
__global__ __launch_bounds__(256, 2) void gemm_accf32(
    const void* __restrict__ A, const void* __restrict__ W, long w_off,
    const void* __restrict__ bias, const u16* __restrict__ resid, long r_row0,
    float* __restrict__ C, int ldw, int init, const int* __restrict__ flags)
{
    GEMM_CORE(A, 0, 0, W, w_off, ldw, 1024)
#pragma unroll
    for (int mt = 0; mt < 4; mt++) {
#pragma unroll
        for (int nt = 0; nt < 4; nt++) {
            const int c = ce0 + nt * 16;
            const float bv = ldx(bias, c, inf32);
#pragma unroll
            for (int i = 0; i < 4; i++) {
                const int r = re0 + mt * 16 + i;
                float v = acc[mt][nt][i];
                if (init) v += bv + bf2f(resid[((size_t)r_row0 + r) * 1024 + c]);
                else      v += C[(size_t)r * 1024 + c];
                C[(size_t)r * 1024 + c] = v;
            }
        }
    }
}

// ---------------------------------------------------------------------------
// Flash attention v3: paired q-tiles (qt, 7-qt) of 128 rows -> uniform 18
// k-tile units/block. Double-buffered K/V staging (prefetch kt+1 before the
// compute of kt; the compiler's vmcnt drain at the single loop barrier lands
// after ~1000 cyc of softmax+MFMA). Mask-bias column preloaded to LDS.
// Grid (4, nbh). In-place Q->O in QO.
// ---------------------------------------------------------------------------
__global__ __launch_bounds__(256, 2) void attn_kernel(
    u16* __restrict__ QO, const u16* __restrict__ Ko,
    const u16* __restrict__ Vt, const float* __restrict__ kb, int b0)
{
    __shared__ __align__(16) u16 Qs[2 * 128 * 32];   // [kcd][qrow][32]
    __shared__ __align__(16) u16 Ks[2][2 * 64 * 32]; // dbuf [kcd][key][32]
    __shared__ __align__(16) u16 Vs[2][2 * 64 * 32]; // dbuf [kck][d][32]
    __shared__ __align__(16) u16 Ps[4][32 * 72];
    __shared__ float kba[1024];

    const int tid  = threadIdx.x;
    const int lane = tid & 63;
    const int w    = tid >> 6;
    const int lc   = lane & 15;
    const int quad = lane >> 4;
    const int bl = blockIdx.y >> 4;
    const int h  = blockIdx.y & 15;
    const int b  = b0 + bl;

    // preload padding-bias column for this sequence
    *(f32x4*)&kba[tid * 4] = *(const f32x4*)&kb[b * 1024 + tid * 4];

    for (int p = 0; p < 2; p++) {
        const int qt = p ? 7 - (int)blockIdx.x : (int)blockIdx.x;

        // stage Q tile [kcd][128][32]
#pragma unroll
        for (int it = 0; it < 4; it++) {
            const int kcd = it >> 1, half = it & 1;
            const int r = half * 64 + (tid >> 2);
            const int c = kcd * 32 + (tid & 3) * 8;
            GLD16(&QO[((size_t)(b * 1024 + qt * 128 + r)) * 1024 + h * 64 + c],
                  &Qs[kcd * 4096 + half * 2048 + tid * 8]);
        }
        // stage kt=0 into buffer 0
        {
            const int rr = tid >> 2;
#pragma unroll
            for (int it = 0; it < 2; it++) {
                const int cc = it * 32 + (tid & 3) * 8;
                GLD16(&Ko[((size_t)(bl * 1024 + rr)) * 1024 + h * 64 + cc],
                      &Ks[0][it * 2048 + tid * 8]);
                GLD16(&Vt[((size_t)(bl * 16 + h) * 64 + rr) * 1024 + cc],
                      &Vs[0][it * 2048 + tid * 8]);
            }
        }
        __syncthreads();   // Q + K0/V0 (+ kba on p=0) ready

        short8 aq[2][2];
#pragma unroll
        for (int mt = 0; mt < 2; mt++)
#pragma unroll
            for (int kc = 0; kc < 2; kc++)
                aq[mt][kc] = *(const short8*)
                    &Qs[kc * 4096 + (w * 32 + mt * 16 + lc) * 32 + quad * 8];

        f32x4 o[2][4] = {};
        float m_i[2][4], l_i[2][4];
#pragma unroll
        for (int mt = 0; mt < 2; mt++)
#pragma unroll
            for (int i = 0; i < 4; i++) { m_i[mt][i] = -1e30f; l_i[mt][i] = 0.0f; }

        const int ktmax = 2 * qt + 2;
        for (int kt = 0; kt < ktmax; kt++) {
            const int cur = kt & 1;
            // prefetch kt+1 (overlaps with compute below; drained at barrier)
            if (kt + 1 < ktmax) {
                const int nxt = cur ^ 1;
                const int rr = tid >> 2;
#pragma unroll
                for (int it = 0; it < 2; it++) {
                    const int cc = it * 32 + (tid & 3) * 8;
                    GLD16(&Ko[((size_t)(bl * 1024 + (kt + 1) * 64 + rr)) * 1024 + h * 64 + cc],
                          &Ks[nxt][it * 2048 + tid * 8]);
                    GLD16(&Vt[((size_t)(bl * 16 + h) * 64 + rr) * 1024 + (kt + 1) * 64 + cc],
                          &Vs[nxt][it * 2048 + tid * 8]);
                }
            }

            // S = Q K^T
            short8 bk[4][2];
#pragma unroll
            for (int nt = 0; nt < 4; nt++)
#pragma unroll
                for (int kc = 0; kc < 2; kc++)
                    bk[nt][kc] = *(const short8*)
                        &Ks[cur][kc * 2048 + (nt * 16 + lc) * 32 + quad * 8];

            f32x4 s[2][4];
#pragma unroll
            for (int mt = 0; mt < 2; mt++)
#pragma unroll
                for (int nt = 0; nt < 4; nt++) {
                    f32x4 z = {};
#pragma unroll
                    for (int kc = 0; kc < 2; kc++)
                        z = __builtin_amdgcn_mfma_f32_16x16x32_bf16(
                            aq[mt][kc], bk[nt][kc], z, 0, 0, 0);
                    s[mt][nt] = z;
                }

            const int causal = (kt >= 2 * qt);   // block-uniform
            float al[2][4];
#pragma unroll
            for (int mt = 0; mt < 2; mt++) {
                const int qg0 = qt * 128 + w * 32 + mt * 16 + quad * 4;
#pragma unroll
                for (int nt = 0; nt < 4; nt++) {
                    const int kg = kt * 64 + nt * 16 + lc;
                    const float kbv = kba[kt * 64 + nt * 16 + lc];
#pragma unroll
                    for (int i = 0; i < 4; i++) {
                        float sv = s[mt][nt][i] + kbv;
                        if (causal && kg > qg0 + i) sv = -1e30f;
                        s[mt][nt][i] = sv;
                    }
                }
                float mnew[4], rs[4];
#pragma unroll
                for (int i = 0; i < 4; i++) {
                    float rm = fmaxf(fmaxf(s[mt][0][i], s[mt][1][i]),
                                     fmaxf(s[mt][2][i], s[mt][3][i]));
                    rm = fmaxf(rm, __shfl_xor(rm, 1));
                    rm = fmaxf(rm, __shfl_xor(rm, 2));
                    rm = fmaxf(rm, __shfl_xor(rm, 4));
                    rm = fmaxf(rm, __shfl_xor(rm, 8));
                    mnew[i] = fmaxf(m_i[mt][i], rm);
                    al[mt][i] = exp2f((m_i[mt][i] - mnew[i]) * 1.442695041f);
                    rs[i] = 0.0f;
                }
#pragma unroll
                for (int nt = 0; nt < 4; nt++)
#pragma unroll
                    for (int i = 0; i < 4; i++) {
                        float pp = exp2f((s[mt][nt][i] - mnew[i]) * 1.442695041f);
                        s[mt][nt][i] = pp;
                        rs[i] += pp;
                    }
#pragma unroll
                for (int i = 0; i < 4; i++) {
                    float r = rs[i];
                    r += __shfl_xor(r, 1);
                    r += __shfl_xor(r, 2);
                    r += __shfl_xor(r, 4);
                    r += __shfl_xor(r, 8);
                    l_i[mt][i] = l_i[mt][i] * al[mt][i] + r;
                    m_i[mt][i] = mnew[i];
                }
#pragma unroll
                for (int nt = 0; nt < 4; nt++)
#pragma unroll
                    for (int i = 0; i < 4; i++)
                        Ps[w][(mt * 16 + quad * 4 + i) * 72 + nt * 16 + lc] =
                            f2bf(s[mt][nt][i]);
            }

            // O = O*alpha + P @ V
            short8 ap[2][2], bv2[4][2];
#pragma unroll
            for (int mt = 0; mt < 2; mt++)
#pragma unroll
                for (int kc = 0; kc < 2; kc++)
                    ap[mt][kc] = *(const short8*)
                        &Ps[w][(mt * 16 + lc) * 72 + kc * 32 + quad * 8];
#pragma unroll
            for (int nt = 0; nt < 4; nt++)
#pragma unroll
                for (int kc = 0; kc < 2; kc++)
                    bv2[nt][kc] = *(const short8*)
                        &Vs[cur][kc * 2048 + (nt * 16 + lc) * 32 + quad * 8];
#pragma unroll
            for (int mt = 0; mt < 2; mt++)
#pragma unroll
                for (int nt = 0; nt < 4; nt++) {
                    f32x4 oo = o[mt][nt];
#pragma unroll
                    for (int i = 0; i < 4; i++) oo[i] *= al[mt][i];
#pragma unroll
                    for (int kc = 0; kc < 2; kc++)
                        oo = __builtin_amdgcn_mfma_f32_16x16x32_bf16(
                            ap[mt][kc], bv2[nt][kc], oo, 0, 0, 0);
                    o[mt][nt] = oo;
                }
            __syncthreads();   // prefetch drained; buffers safe to swap
        }

        // write O in place of Q (exclusive slice)
#pragma unroll
        for (int mt = 0; mt < 2; mt++)
#pragma unroll
            for (int i = 0; i < 4; i++) {
                const float inv = l_i[mt][i] > 0.0f ? 1.0f / l_i[mt][i] : 0.0f;
#pragma unroll
                for (int nt = 0; nt < 4; nt++) {
                    const int r = qt * 128 + w * 32 + mt * 16 + quad * 4 + i;
                    const int d = nt * 16 + lc;
                    QO[((size_t)(b * 1024 + r)) * 1024 + h * 64 + d] =
                        f2bf(o[mt][nt][i] * inv);
                }
            }
    }
}

// ---------------------------------------------------------------------------
// LayerNorm, one block/row, biased variance, eps=1e-12.
// ---------------------------------------------------------------------------
template<int IN16, int OUTSEL>
__global__ __launch_bounds__(256) void ln_kernel(
    const void* __restrict__ yv, const void* __restrict__ w,
    const void* __restrict__ bb, void* __restrict__ o, long o_row0,
    const int* __restrict__ flags)
{
    const int row = blockIdx.x;
    const int tid = threadIdx.x;
    const int inf32 = flags[0];
    float x0, x1, x2, x3;
    if (IN16) {
        const u16* p = (const u16*)yv + (size_t)row * 1024 + tid * 4;
        short4v v = *(const short4v*)p;
        x0 = bf2f((u16)v[0]); x1 = bf2f((u16)v[1]);
        x2 = bf2f((u16)v[2]); x3 = bf2f((u16)v[3]);
    } else {
        const float* p = (const float*)yv + (size_t)row * 1024 + tid * 4;
        f32x4 v = *(const f32x4*)p;
        x0 = v[0]; x1 = v[1]; x2 = v[2]; x3 = v[3];
    }
    float s = x0 + x1 + x2 + x3;
    float q = x0 * x0 + x1 * x1 + x2 * x2 + x3 * x3;
#pragma unroll
    for (int off = 32; off; off >>= 1) {
        s += __shfl_xor(s, off);
        q += __shfl_xor(q, off);
    }
    __shared__ float sm[8];
    const int lane = tid & 63, wv = tid >> 6;
    if (lane == 0) { sm[wv] = s; sm[4 + wv] = q; }
    __syncthreads();
    const float ts = sm[0] + sm[1] + sm[2] + sm[3];
    const float tq = sm[4] + sm[5] + sm[6] + sm[7];
    const float mean = ts * (1.0f / 1024.0f);
    float var = tq * (1.0f / 1024.0f) - mean * mean;
    if (var < 0.0f) var = 0.0f;
    const float rinv = rsqrtf(var + 1e-12f);

    const size_t obase = ((size_t)o_row0 + row) * 1024 + tid * 4;
#pragma unroll
    for (int j = 0; j < 4; j++) {
        const int c = tid * 4 + j;
        float xv = (j == 0) ? x0 : (j == 1) ? x1 : (j == 2) ? x2 : x3;
        float v = ldx(w, c, inf32) * ((xv - mean) * rinv) + ldx(bb, c, inf32);
        if (OUTSEL && inf32) ((float*)o)[obase + j] = v;
        else                 ((u16*)o)[obase + j] = f2bf(v);
    }
}

// ---------------------------------------------------------------------------
extern "C" void kernel_launch(void* const* d_in, const int* in_sizes, int n_in,
                              void* d_out, int out_size, void* d_ws, size_t ws_size,
                              hipStream_t stream)
{
    const void* x     = d_in[0];
    const void* in_w  = d_in[1];
    const void* in_b  = d_in[2];
    const void* out_w = d_in[3];
    const void* out_b = d_in[4];
    const void* fc1_w = d_in[5];
    const void* fc1_b = d_in[6];
    const void* fc2_w = d_in[7];
    const void* fc2_b = d_in[8];
    const void* ln1w  = d_in[9];
    const void* ln1b  = d_in[10];
    const void* ln2w  = d_in[11];
    const void* ln2b  = d_in[12];
    const void* pad   = d_in[13];
    u16* outp = (u16*)d_out;
    char* ws = (char*)d_ws;
    dim3 blk(256);

    const size_t MB = 1024 * 1024;
    const bool bigWS = ws_size >= (105 * MB + 64 * 1024);

    if (bigWS) {
        // Tier A layout:
        //  0-16  xb -> x1        16-22 w1b (dead after qkv) \
        //  22-24 wob (dead after proj)  24-32 f1b (dead after fc1) } -> y2 16-32
        //  32-40 f2b   40-41 biases     41-57 Ko    57-73 Vt
        //  73-89 y1    41-105 h (FF)    105+ flags / kbias
        u16*   xb   = (u16*)(ws + 0);
        u16*   x1   = (u16*)(ws + 0);
        u16*   w1b  = (u16*)(ws + 16 * MB);
        u16*   wob  = (u16*)(ws + 22 * MB);
        u16*   f1b  = (u16*)(ws + 24 * MB);
        u16*   f2b  = (u16*)(ws + 32 * MB);
        u16*   inbb = (u16*)(ws + 40 * MB);
        u16*   outbb= (u16*)(ws + 40 * MB + 8192);
        u16*   f1bb = (u16*)(ws + 40 * MB + 16384);
        u16*   f2bb = (u16*)(ws + 40 * MB + 24576);
        u16*   Ko   = (u16*)(ws + 41 * MB);
        u16*   Vt   = (u16*)(ws + 57 * MB);
        u16*   y1   = (u16*)(ws + 73 * MB);
        u16*   h    = (u16*)(ws + 41 * MB);
        u16*   y2   = (u16*)(ws + 16 * MB);
        int*   flags  = (int*)(ws + 105 * MB);
        int*   flagsA = (int*)(ws + 105 * MB + 32);
        float* kbias  = (float*)(ws + 105 * MB + 64);

        probe_kernel<<<dim3(1), dim3(64), 0, stream>>>(x, pad, flags, flagsA);
        mask_to_bias<<<dim3(32), blk, 0, stream>>>(pad, kbias, flags);
        conv4<<<dim3(8192), blk, 0, stream>>>(x, xb, 2097152, flags);
        conv4<<<dim3(3072), blk, 0, stream>>>(in_w, w1b, 786432, flags);
        conv4<<<dim3(1024), blk, 0, stream>>>(out_w, wob, 262144, flags);
        conv4<<<dim3(4096), blk, 0, stream>>>(fc1_w, f1b, 1048576, flags);
        conv4<<<dim3(4096), blk, 0, stream>>>(fc2_w, f2b, 1048576, flags);
        conv4<<<dim3(3), blk, 0, stream>>>(in_b, inbb, 768, flags);
        conv4<<<dim3(1), blk, 0, stream>>>(out_b, outbb, 256, flags);
        conv4<<<dim3(4), blk, 0, stream>>>(fc1_b, f1bb, 1024, flags);
        conv4<<<dim3(1), blk, 0, stream>>>(fc2_b, f2bb, 256, flags);

        gemm_qkv<<<dim3(64, 24), blk, 0, stream>>>(
            xb, 0, w1b, inbb, outp, Ko, Vt, flagsA);
        attn_kernel<<<dim3(4, 128), blk, 0, stream>>>(outp, Ko, Vt, kbias, 0);
        gemm_bt<1><<<dim3(64, 8), blk, 0, stream>>>(
            outp, 0, 0, wob, 0, outbb, 0, xb, 0, 0, y1, 0, 1024, 1024, 1024, flagsA);
        ln_kernel<1, 0><<<dim3(8192), blk, 0, stream>>>(y1, ln1w, ln1b, x1, 0, flags);
        // fc1 full: h = relu(x1 @ f1b^T + f1bb)   [8192, 4096]
        gemm_bt<2><<<dim3(64, 32), blk, 0, stream>>>(
            x1, 0, 0, f1b, 0, f1bb, 0, nullptr, 0, 0, h, 0, 4096, 1024, 1024, flagsA);
        // fc2 full-M, K=4096, bf16 out + residual
        gemm_bt<1><<<dim3(64, 8), blk, 0, stream>>>(
            h, 0, 0, f2b, 0, f2bb, 0, x1, 0, 0, y2, 0, 1024, 4096, 4096, flagsA);
        ln_kernel<1, 1><<<dim3(8192), blk, 0, stream>>>(y2, ln2w, ln2b, d_out, 0, flags);
    } else {
        // Tier C: quartered, 12.6 MB workspace
        u16*   Ko    = (u16*)(ws + 0);
        u16*   Vt    = (u16*)(ws + 4 * MB);
        u16*   y1h   = (u16*)(ws + 0);
        float* acc   = (float*)(ws + 0);
        u16*   hc    = (u16*)(ws + 8 * MB);
        int*   flags  = (int*)(ws + 12 * MB);
        int*   flagsA = (int*)(ws + 12 * MB + 32);
        float* kbias  = (float*)(ws + 12 * MB + 64);

        probe_kernel<<<dim3(1), dim3(64), 0, stream>>>(x, pad, flags, flagsA);
        mask_to_bias<<<dim3(32), blk, 0, stream>>>(pad, kbias, flags);

        for (int q = 0; q < 4; q++) {
            const long r0 = (long)q * 2048;
            gemm_qkv<<<dim3(16, 24), blk, 0, stream>>>(
                x, r0, in_w, in_b, outp, Ko, Vt, flags);
            attn_kernel<<<dim3(4, 32), blk, 0, stream>>>(
                outp, Ko, Vt, kbias, q * 2);
        }
        for (int hf = 0; hf < 2; hf++) {
            const long r0 = (long)hf * 4096;
            gemm_bt<1><<<dim3(32, 8), blk, 0, stream>>>(
                outp, 0, r0, out_w, 0, out_b, 0, x, 1, r0,
                y1h, 0, 1024, 1024, 1024, flags);
            ln_kernel<1, 0><<<dim3(4096), blk, 0, stream>>>(
                y1h, ln1w, ln1b, outp, r0, flags);
        }
        for (int q = 3; q >= 0; q--) {
            const long r0 = (long)q * 2048;
            for (int c = 0; c < 4; c++) {
                gemm_bt<2><<<dim3(16, 8), blk, 0, stream>>>(
                    outp, 0, r0, fc1_w, (long)c * 1024 * 1024, fc1_b, (long)c * 1024,
                    nullptr, 0, 0, hc, 0, 1024, 1024, 1024, flags);
                gemm_accf32<<<dim3(16, 8), blk, 0, stream>>>(
                    hc, fc2_w, (long)c * 1024, fc2_b, outp, r0,
                    acc, 4096, c == 0, flags);
            }
            ln_kernel<0, 1><<<dim3(2048), blk, 0, stream>>>(
                acc, ln2w, ln2b, d_out, r0, flags);
        }
    }
}